// Round 11
// baseline (178.504 us; speedup 1.0000x reference)
//
#include <hip/hip_runtime.h>
#include <hip/hip_fp16.h>
#include <stdint.h>

typedef _Float16 f16;
typedef __attribute__((ext_vector_type(8))) _Float16 f16x8;
typedef __attribute__((ext_vector_type(4))) _Float16 f16x4;
typedef __attribute__((ext_vector_type(4))) float f32x4;

#define SEQ 2048
#define DIM 1024
#define NBATCH 2
#define MTOT 4096  // NBATCH*SEQ

__global__ void fill_kernel(float* p, float v, int n){
  int i = blockIdx.x * 256 + threadIdx.x;
  if (i < n) p[i] = v;
}

// fp32->fp16 converts: blocks 0..4095 -> x, 4096..8191 -> weights,
// block 8192 -> zero the 256 pair-tickets (every call: deterministic replay).
__global__ void cvt_all(const float* __restrict__ x, const float* __restrict__ Wq,
                        const float* __restrict__ Wk, const float* __restrict__ Wv,
                        const float* __restrict__ Wo,
                        f16* __restrict__ x16, f16* __restrict__ Wcat, f16* __restrict__ Wo16,
                        int* __restrict__ ticket){
  int b = blockIdx.x;
  if (b == 8192){
    ticket[threadIdx.x] = 0;
    return;
  }
  const float* src; f16* dst; int i;
  if (b < 4096){
    src = x; dst = x16; i = b * 256 + threadIdx.x;
  } else {
    int t = (b - 4096) >> 10;
    i = ((b - 4096) & 1023) * 256 + threadIdx.x;
    src = t == 0 ? Wq : t == 1 ? Wk : t == 2 ? Wv : Wo;
    dst = (t == 3) ? Wo16 : Wcat + (size_t)t * DIM * DIM;
  }
  float4 v = ((const float4*)src)[i];
  ((f16x4*)dst)[i] = (f16x4){(f16)v.x, (f16)v.y, (f16)v.z, (f16)v.w};
}

#define GLOAD16(SRC, DST) __builtin_amdgcn_global_load_lds( \
    (__attribute__((address_space(1))) void*)(SRC), \
    (__attribute__((address_space(3))) void*)(DST), 16, 0, 0)

// theta -> unnormalized exp (shift 10, clamp 11). x->-inf: e1=inf -> sg=0, th=-1.
__device__ __forceinline__ float theta_exp(float v){
  const float e1 = __expf(-v);
  const float sg = 1.f / (1.f + e1);
  const float e2 = e1 * e1;             // e^{-2x}
  const float th = 2.f / (1.f + e2) - 1.f;
  const float theta = 0.5f + 0.2f * sg + 0.15f * th + 0.1f * fmaxf(v, 0.f);
  return __expf(fminf(theta - 10.f, 11.f));
}

// ---------------------------------------------------------------------------
// qkv: 256-thr 128x128 tile, BK=64, single-buffer, 2 barriers/tile. XOR
// swizzle: LDS[r][cb] = G[r][cb^(r&7)], linear gload_lds dest + pre-swizzled
// source; reads apply same XOR (0 conflicts measured R3-R10). K-loop unrolled.
// Grid (32,24) = 768 = 3/CU. ~860 TF measured (shape ceiling).
// ---------------------------------------------------------------------------
__global__ __launch_bounds__(256, 3)
void gemm_qkv(const f16* __restrict__ A0, const f16* __restrict__ B0,
              f16* __restrict__ O0, f16* __restrict__ O1,
              const float* __restrict__ c0, const float* __restrict__ c1,
              const float* __restrict__ c2)
{
  __shared__ __align__(16) f16 As[8192];   // 128 x 64 f16
  __shared__ __align__(16) f16 Bs[8192];
  const int tid  = threadIdx.x;
  const int lane = tid & 63;
  const int wid  = tid >> 6;
  const int bm = blockIdx.x, bn = blockIdx.y;

  const int s_r  = tid >> 3;            // 0..31
  const int s_cb = (tid & 7) ^ (s_r & 7);
  const f16* Ab = A0 + (long)(bm * 128 + s_r) * DIM + s_cb * 8;
  const f16* Bb = B0 + (long)(bn * 128 + s_r) * DIM + s_cb * 8;

  const int l15 = lane & 15, l7 = lane & 7, lhi = lane >> 4;
  const int wrow = (wid >> 1) * 64;
  const int wcol = (wid & 1) * 64;
  const int ar = (wrow + l15) * 64;
  const int br = (wcol + l15) * 64;
  const int cb0 = ((0 + lhi) ^ l7) * 8;
  const int cb1 = ((4 + lhi) ^ l7) * 8;

  f32x4 acc[4][4] = {};

#pragma unroll
  for (int t = 0; t < 16; ++t){
    __syncthreads();
    GLOAD16(Ab + (long)t*64,                  &As[       tid*8]);
    GLOAD16(Ab + (long)t*64 + (long)32 * DIM, &As[2048 + tid*8]);
    GLOAD16(Ab + (long)t*64 + (long)64 * DIM, &As[4096 + tid*8]);
    GLOAD16(Ab + (long)t*64 + (long)96 * DIM, &As[6144 + tid*8]);
    GLOAD16(Bb + (long)t*64,                  &Bs[       tid*8]);
    GLOAD16(Bb + (long)t*64 + (long)32 * DIM, &Bs[2048 + tid*8]);
    GLOAD16(Bb + (long)t*64 + (long)64 * DIM, &Bs[4096 + tid*8]);
    GLOAD16(Bb + (long)t*64 + (long)96 * DIM, &Bs[6144 + tid*8]);
    __syncthreads();
    f16x8 af[4], bf[4];
#pragma unroll
    for (int i = 0; i < 4; i++) af[i] = *(const f16x8*)&As[ar + i * 1024 + cb0];
#pragma unroll
    for (int j = 0; j < 4; j++) bf[j] = *(const f16x8*)&Bs[br + j * 1024 + cb0];
#pragma unroll
    for (int i = 0; i < 4; i++)
#pragma unroll
      for (int j = 0; j < 4; j++)
        acc[i][j] = __builtin_amdgcn_mfma_f32_16x16x32_f16(af[i], bf[j], acc[i][j], 0, 0, 0);
#pragma unroll
    for (int i = 0; i < 4; i++) af[i] = *(const f16x8*)&As[ar + i * 1024 + cb1];
#pragma unroll
    for (int j = 0; j < 4; j++) bf[j] = *(const f16x8*)&Bs[br + j * 1024 + cb1];
#pragma unroll
    for (int i = 0; i < 4; i++)
#pragma unroll
      for (int j = 0; j < 4; j++)
        acc[i][j] = __builtin_amdgcn_mfma_f32_16x16x32_f16(af[i], bf[j], acc[i][j], 0, 0, 0);
  }

  const int cc = l15;
  const int rr = lhi * 4;
#pragma unroll
  for (int i = 0; i < 4; i++)
#pragma unroll
    for (int j = 0; j < 4; j++){
      const int col = bn * 128 + wcol + j * 16 + cc;
      if (col < 2048){
        const float badd = (col < 1024) ? c0[col] : c1[col - 1024];
#pragma unroll
        for (int r = 0; r < 4; r++){
          const int row = bm * 128 + wrow + i * 16 + rr + r;
          O0[(long)row * 2048 + col] = (f16)(acc[i][j][r] + badd);
        }
      } else {
        const int dcol = col - 2048;
        const float badd = c2[dcol];
#pragma unroll
        for (int r = 0; r < 4; r++){
          const int row = bm * 128 + wrow + i * 16 + rr + r;
          O1[(long)row * DIM + dcol] = (f16)(acc[i][j][r] + badd);
        }
      }
    }
}

// ---------------------------------------------------------------------------
// Merged qk + vWo (128x128 tiles, 512 + 256 = 768 blocks, 3/CU), XCD remap
// (r%8 -> XCD heuristic; correctness-independent). Row sums are computed by
// the final kernel from its staged P tiles (atomic-free).
//   qk (r<512):   P = theta_exp(q@k^T) -> Pbuf (f16).
//   vWo (r>=512): (v@Wo^T)^T -> vWoT[b][e][t] (f16x4 scatter).
// ---------------------------------------------------------------------------
__global__ __launch_bounds__(256, 3)
void gemm_merged(const f16* __restrict__ qkcat, const f16* __restrict__ vbuf,
                 const f16* __restrict__ Wo16,
                 f16* __restrict__ Pbuf, f16* __restrict__ vWoT)
{
  __shared__ __align__(16) f16 As[8192];
  __shared__ __align__(16) f16 Bs[8192];
  const int tid  = threadIdx.x;
  const int lane = tid & 63;
  const int wid  = tid >> 6;
  const int l15 = lane & 15, l7 = lane & 7, lhi = lane >> 4;
  const int s_r  = tid >> 3;
  const int s_cb = (tid & 7) ^ (s_r & 7);
  const int cb0 = ((0 + lhi) ^ l7) * 8;
  const int cb1 = ((4 + lhi) ^ l7) * 8;
  const int cc = l15, rr = lhi * 4;
  const int wrow = (wid >> 1) * 64;
  const int wcol = (wid & 1) * 64;
  const int ar = (wrow + l15) * 64;
  const int br = (wcol + l15) * 64;
  const int r = blockIdx.x;

  if (r < 512){
    // ---------------- qk path: 128x128, ld 2048 ----------------
    const int x = r & 7, i5 = r >> 3;
    const int bz = x >> 2;
    const int bn = (x & 3) * 4 + (i5 & 3);
    const int bm = i5 >> 2;
    const f16* Ab = qkcat + (long)bz * SEQ * 2048 + (long)(bm * 128 + s_r) * 2048 + s_cb * 8;
    const f16* Bb = qkcat + DIM + (long)bz * SEQ * 2048 + (long)(bn * 128 + s_r) * 2048 + s_cb * 8;

    f32x4 acc[4][4] = {};

#pragma unroll
    for (int t = 0; t < 16; ++t){
      __syncthreads();
      GLOAD16(Ab + (long)t*64,                   &As[       tid*8]);
      GLOAD16(Ab + (long)t*64 + (long)32 * 2048, &As[2048 + tid*8]);
      GLOAD16(Ab + (long)t*64 + (long)64 * 2048, &As[4096 + tid*8]);
      GLOAD16(Ab + (long)t*64 + (long)96 * 2048, &As[6144 + tid*8]);
      GLOAD16(Bb + (long)t*64,                   &Bs[       tid*8]);
      GLOAD16(Bb + (long)t*64 + (long)32 * 2048, &Bs[2048 + tid*8]);
      GLOAD16(Bb + (long)t*64 + (long)64 * 2048, &Bs[4096 + tid*8]);
      GLOAD16(Bb + (long)t*64 + (long)96 * 2048, &Bs[6144 + tid*8]);
      __syncthreads();
      f16x8 af[4], bf[4];
#pragma unroll
      for (int i = 0; i < 4; i++) af[i] = *(const f16x8*)&As[ar + i * 1024 + cb0];
#pragma unroll
      for (int j = 0; j < 4; j++) bf[j] = *(const f16x8*)&Bs[br + j * 1024 + cb0];
#pragma unroll
      for (int i = 0; i < 4; i++)
#pragma unroll
        for (int j = 0; j < 4; j++)
          acc[i][j] = __builtin_amdgcn_mfma_f32_16x16x32_f16(af[i], bf[j], acc[i][j], 0, 0, 0);
#pragma unroll
      for (int i = 0; i < 4; i++) af[i] = *(const f16x8*)&As[ar + i * 1024 + cb1];
#pragma unroll
      for (int j = 0; j < 4; j++) bf[j] = *(const f16x8*)&Bs[br + j * 1024 + cb1];
#pragma unroll
      for (int i = 0; i < 4; i++)
#pragma unroll
        for (int j = 0; j < 4; j++)
          acc[i][j] = __builtin_amdgcn_mfma_f32_16x16x32_f16(af[i], bf[j], acc[i][j], 0, 0, 0);
    }

#pragma unroll
    for (int i = 0; i < 4; i++)
#pragma unroll
      for (int rq = 0; rq < 4; rq++){
        const int row = bm * 128 + wrow + i * 16 + rr + rq;
#pragma unroll
        for (int j = 0; j < 4; j++){
          const int col = bn * 128 + wcol + j * 16 + cc;
          Pbuf[(long)bz * SEQ * SEQ + (long)row * SEQ + col] = (f16)theta_exp(acc[i][j][rq]);
        }
      }
  } else {
    // ---------------- vWo path: 128x128, ld 1024 ----------------
    const int rr2 = r - 512;
    const int x = rr2 & 7, i5 = rr2 >> 3;
    const int bz = x >> 2;
    const int bn = (x & 3) * 2 + (i5 & 1);
    const int bm = i5 >> 1;
    const f16* Ab = vbuf + (long)bz * SEQ * DIM + (long)(bm * 128 + s_r) * DIM + s_cb * 8;
    const f16* Bb = Wo16 + (long)(bn * 128 + s_r) * DIM + s_cb * 8;

    f32x4 acc[4][4] = {};

#pragma unroll
    for (int t = 0; t < 16; ++t){
      __syncthreads();
      GLOAD16(Ab + (long)t*64,                  &As[       tid*8]);
      GLOAD16(Ab + (long)t*64 + (long)32 * DIM, &As[2048 + tid*8]);
      GLOAD16(Ab + (long)t*64 + (long)64 * DIM, &As[4096 + tid*8]);
      GLOAD16(Ab + (long)t*64 + (long)96 * DIM, &As[6144 + tid*8]);
      GLOAD16(Bb + (long)t*64,                  &Bs[       tid*8]);
      GLOAD16(Bb + (long)t*64 + (long)32 * DIM, &Bs[2048 + tid*8]);
      GLOAD16(Bb + (long)t*64 + (long)64 * DIM, &Bs[4096 + tid*8]);
      GLOAD16(Bb + (long)t*64 + (long)96 * DIM, &Bs[6144 + tid*8]);
      __syncthreads();
      f16x8 af[4], bf[4];
#pragma unroll
      for (int i = 0; i < 4; i++) af[i] = *(const f16x8*)&As[ar + i * 1024 + cb0];
#pragma unroll
      for (int j = 0; j < 4; j++) bf[j] = *(const f16x8*)&Bs[br + j * 1024 + cb0];
#pragma unroll
      for (int i = 0; i < 4; i++)
#pragma unroll
        for (int j = 0; j < 4; j++)
          acc[i][j] = __builtin_amdgcn_mfma_f32_16x16x32_f16(af[i], bf[j], acc[i][j], 0, 0, 0);
#pragma unroll
      for (int i = 0; i < 4; i++) af[i] = *(const f16x8*)&As[ar + i * 1024 + cb1];
#pragma unroll
      for (int j = 0; j < 4; j++) bf[j] = *(const f16x8*)&Bs[br + j * 1024 + cb1];
#pragma unroll
      for (int i = 0; i < 4; i++)
#pragma unroll
        for (int j = 0; j < 4; j++)
          acc[i][j] = __builtin_amdgcn_mfma_f32_16x16x32_f16(af[i], bf[j], acc[i][j], 0, 0, 0);
    }

#pragma unroll
    for (int i = 0; i < 4; i++)
#pragma unroll
      for (int j = 0; j < 4; j++){
        const int col = bn * 128 + wcol + j * 16 + cc;       // e
        const int row0 = bm * 128 + wrow + i * 16 + rr;      // t (4 consecutive)
        f16x4 pk = {(f16)acc[i][j][0], (f16)acc[i][j][1],
                    (f16)acc[i][j][2], (f16)acc[i][j][3]};
        *(f16x4*)&vWoT[(long)bz * DIM * SEQ + (long)col * SEQ + row0] = pk;
      }
  }
}

// ---------------------------------------------------------------------------
// Final split-K=2 WITH INLINE COMBINE (ticket handshake, no combine kernel).
// Grid (16,8,4) = 1024 blocks, 4/CU. Per block: 128x128 fp32 partial over one
// K-half + atomic-free row sums (even waves sum af P-fragments; identical
// bits across bn blocks -> redundant stores benign).
// Epilogue: store psum + rowsum; syncthreads (drains stores); thread0
// threadfence + atomicAdd(ticket[pair]); the block drawing old==1 re-fences,
// reads sibling psum tile (L2/L3-hot) + both rowsum slices, writes
// out = (acc + sib)/(rs0+rs1) + bo. Deterministic across replays: winner may
// swap but (a+b) is IEEE-commutative and all stored values are bit-stable.
// ---------------------------------------------------------------------------
__global__ __launch_bounds__(256, 4)
void gemm_final(const f16* __restrict__ Pb, const f16* __restrict__ Vw,
                float* __restrict__ psum, float* __restrict__ rowsum,
                int* __restrict__ ticket, const float* __restrict__ bo,
                float* __restrict__ out)
{
  __shared__ __align__(16) f16 As[8192];
  __shared__ __align__(16) f16 Bs[8192];
  __shared__ int s_old;
  const int tid  = threadIdx.x;
  const int lane = tid & 63;
  const int wid  = tid >> 6;
  const int bm = blockIdx.x, bn = blockIdx.y;
  const int bz = blockIdx.z >> 1, kh = blockIdx.z & 1;

  const f16* Ag = Pb + (long)bz * SEQ * SEQ + (long)kh * 1024;
  const f16* Bg = Vw + (long)bz * DIM * SEQ + (long)kh * 1024;

  const int s_r  = tid >> 3;
  const int s_cb = (tid & 7) ^ (s_r & 7);
  const f16* Ab = Ag + (long)(bm * 128 + s_r) * 2048 + s_cb * 8;
  const f16* Bb = Bg + (long)(bn * 128 + s_r) * 2048 + s_cb * 8;

  const int l15 = lane & 15, l7 = lane & 7, lhi = lane >> 4;
  const int wrow = (wid >> 1) * 64;
  const int wcol = (wid & 1) * 64;
  const int ar = (wrow + l15) * 64;
  const int br = (wcol + l15) * 64;
  const int cb0 = ((0 + lhi) ^ l7) * 8;
  const int cb1 = ((4 + lhi) ^ l7) * 8;
  const bool do_rs = ((wid & 1) == 0);

  f32x4 acc[4][4] = {};
  float rsum[4] = {0.f, 0.f, 0.f, 0.f};

#pragma unroll
  for (int t = 0; t < 16; ++t){
    __syncthreads();
    GLOAD16(Ab + (long)t*64,                   &As[       tid*8]);
    GLOAD16(Ab + (long)t*64 + (long)32 * 2048, &As[2048 + tid*8]);
    GLOAD16(Ab + (long)t*64 + (long)64 * 2048, &As[4096 + tid*8]);
    GLOAD16(Ab + (long)t*64 + (long)96 * 2048, &As[6144 + tid*8]);
    GLOAD16(Bb + (long)t*64,                   &Bs[       tid*8]);
    GLOAD16(Bb + (long)t*64 + (long)32 * 2048, &Bs[2048 + tid*8]);
    GLOAD16(Bb + (long)t*64 + (long)64 * 2048, &Bs[4096 + tid*8]);
    GLOAD16(Bb + (long)t*64 + (long)96 * 2048, &Bs[6144 + tid*8]);
    __syncthreads();
    f16x8 af[4], bf[4];
#pragma unroll
    for (int i = 0; i < 4; i++) af[i] = *(const f16x8*)&As[ar + i * 1024 + cb0];
#pragma unroll
    for (int j = 0; j < 4; j++) bf[j] = *(const f16x8*)&Bs[br + j * 1024 + cb0];
#pragma unroll
    for (int i = 0; i < 4; i++)
#pragma unroll
      for (int j = 0; j < 4; j++)
        acc[i][j] = __builtin_amdgcn_mfma_f32_16x16x32_f16(af[i], bf[j], acc[i][j], 0, 0, 0);
    if (do_rs){
#pragma unroll
      for (int i = 0; i < 4; i++)
#pragma unroll
        for (int e = 0; e < 8; e++) rsum[i] += (float)af[i][e];
    }
#pragma unroll
    for (int i = 0; i < 4; i++) af[i] = *(const f16x8*)&As[ar + i * 1024 + cb1];
#pragma unroll
    for (int j = 0; j < 4; j++) bf[j] = *(const f16x8*)&Bs[br + j * 1024 + cb1];
#pragma unroll
    for (int i = 0; i < 4; i++)
#pragma unroll
      for (int j = 0; j < 4; j++)
        acc[i][j] = __builtin_amdgcn_mfma_f32_16x16x32_f16(af[i], bf[j], acc[i][j], 0, 0, 0);
    if (do_rs){
#pragma unroll
      for (int i = 0; i < 4; i++)
#pragma unroll
        for (int e = 0; e < 8; e++) rsum[i] += (float)af[i][e];
    }
  }

  // row sums: reduce over lhi (4 lanes hold disjoint col chunks of same row);
  // every block stores (identical bits across bn -> benign redundant writes).
  if (do_rs){
#pragma unroll
    for (int i = 0; i < 4; i++){
      rsum[i] += __shfl_xor(rsum[i], 16, 64);
      rsum[i] += __shfl_xor(rsum[i], 32, 64);
    }
    if (lane < 16){
#pragma unroll
      for (int i = 0; i < 4; i++)
        rowsum[(long)kh * MTOT + bz * SEQ + bm * 128 + wrow + i * 16 + lane] = rsum[i];
    }
  }

  const int cc = l15;
  const int rr = lhi * 4;
  float* Po = psum + (long)kh * MTOT * DIM + (long)bz * SEQ * DIM;
#pragma unroll
  for (int i = 0; i < 4; i++)
#pragma unroll
    for (int j = 0; j < 4; j++){
      const int col = bn * 128 + wcol + j * 16 + cc;
#pragma unroll
      for (int r = 0; r < 4; r++){
        const int row = bm * 128 + wrow + i * 16 + rr + r;
        Po[(long)row * DIM + col] = acc[i][j][r];
      }
    }

  // ---- ticket handshake: second block of the (bm,bn,bz) pair combines ----
  __syncthreads();                      // all waves' psum/rowsum stores drained
  if (tid == 0){
    __threadfence();                    // release: flush to device scope
    s_old = atomicAdd(&ticket[(bz * 16 + bm) * 8 + bn], 1);
  }
  __syncthreads();
  if (s_old == 1){
    __threadfence();                    // acquire side
    const float* Ps = psum + (long)(kh ^ 1) * MTOT * DIM + (long)bz * SEQ * DIM;
    const float* rs0 = rowsum;
    const float* rs1 = rowsum + MTOT;
    float* Ob = out + (long)bz * SEQ * DIM;
#pragma unroll
    for (int i = 0; i < 4; i++)
#pragma unroll
      for (int r = 0; r < 4; r++){
        const int row = bm * 128 + wrow + i * 16 + rr + r;
        const float inv = 1.f / (rs0[bz * SEQ + row] + rs1[bz * SEQ + row]);
#pragma unroll
        for (int j = 0; j < 4; j++){
          const int col = bn * 128 + wcol + j * 16 + cc;
          const float sib = Ps[(long)row * DIM + col];
          Ob[(long)row * DIM + col] = (acc[i][j][r] + sib) * inv + bo[col];
        }
      }
  }
}

extern "C" void kernel_launch(void* const* d_in, const int* in_sizes, int n_in,
                              void* d_out, int out_size, void* d_ws, size_t ws_size,
                              hipStream_t stream){
  const float* x  = (const float*)d_in[0];
  const float* Wq = (const float*)d_in[1];
  const float* bq = (const float*)d_in[2];
  const float* Wk = (const float*)d_in[3];
  const float* bk = (const float*)d_in[4];
  const float* Wv = (const float*)d_in[5];
  const float* bv = (const float*)d_in[6];
  const float* Wo = (const float*)d_in[7];
  const float* bo = (const float*)d_in[8];
  float* out = (float*)d_out;

  char* ws = (char*)d_ws;
  size_t off = 0;
  auto alloc = [&](size_t bytes) -> char* {
    char* p = ws + off; off += (bytes + 255) & ~(size_t)255; return p;
  };

  f16* x16     = (f16*)alloc(2ull * MTOT * DIM);          // 8 MB
  f16* Wcat    = (f16*)alloc(2ull * 3 * DIM * DIM);       // 6 MB  [Wq;Wk;Wv]
  f16* Wo16    = (f16*)alloc(2ull * DIM * DIM);           // 2 MB
  f16* qkcat   = (f16*)alloc(2ull * MTOT * 2 * DIM);      // 16 MB [q|k] per row
  f16* vbuf    = (f16*)alloc(2ull * MTOT * DIM);          // 8 MB  v row-major
  f16* Pbuf    = (f16*)alloc(2ull * NBATCH * SEQ * SEQ);  // 16 MB unnormalized exp
  f16* vWoT    = (f16*)alloc(2ull * NBATCH * DIM * SEQ);  // 8 MB  (v@Wo^T)^T [b][e][t]
  float* psum  = (float*)alloc(4ull * 2 * MTOT * DIM);    // 32 MB split-K partials
  float* rowsm = (float*)alloc(4ull * 2 * MTOT);          // 32 KB partial row sums
  int* ticket  = (int*)alloc(4ull * 256);                 // 1 KB pair tickets

  if (off > ws_size){
    fill_kernel<<<(out_size + 255) / 256, 256, 0, stream>>>(out, 12345.0f, out_size);
    return;
  }

  // converts + ticket zeroing (every call)
  cvt_all<<<8193, 256, 0, stream>>>(x, Wq, Wk, Wv, Wo, x16, Wcat, Wo16, ticket);

  // fused [q|k|v] = x @ [Wq;Wk;Wv]^T + bias  (grid 32x24 = 768 blocks, 3/CU)
  gemm_qkv<<<dim3(MTOT / 128, 3 * DIM / 128, 1), 256, 0, stream>>>(
      x16, Wcat, qkcat, vbuf, bq, bk, bv);

  // merged: qk->P [0..511] and vWo^T [512..767], XCD-remapped, 3/CU
  gemm_merged<<<768, 256, 0, stream>>>(qkcat, vbuf, Wo16, Pbuf, vWoT);

  // split-K=2 partials + row sums + inline combine (grid 16x8x4, 4/CU)
  gemm_final<<<dim3(SEQ / 128, DIM / 128, 2 * NBATCH), 256, 0, stream>>>(
      Pbuf, vWoT, psum, rowsm, ticket, bo, out);
}

// Round 12
// 119.677 us; speedup vs baseline: 1.4915x; 1.4915x over previous
//
#include <hip/hip_runtime.h>
#include <hip/hip_fp16.h>
#include <stdint.h>

typedef _Float16 f16;
typedef __attribute__((ext_vector_type(8))) _Float16 f16x8;
typedef __attribute__((ext_vector_type(4))) _Float16 f16x4;
typedef __attribute__((ext_vector_type(4))) float f32x4;

#define SEQ 2048
#define DIM 1024
#define NBATCH 2
#define MTOT 4096  // NBATCH*SEQ

__global__ void fill_kernel(float* p, float v, int n){
  int i = blockIdx.x * 256 + threadIdx.x;
  if (i < n) p[i] = v;
}

// fp32->fp16 converts: blocks 0..4095 -> x, 4096..8191 -> weights.
__global__ void cvt_all(const float* __restrict__ x, const float* __restrict__ Wq,
                        const float* __restrict__ Wk, const float* __restrict__ Wv,
                        const float* __restrict__ Wo,
                        f16* __restrict__ x16, f16* __restrict__ Wcat, f16* __restrict__ Wo16){
  int b = blockIdx.x;
  const float* src; f16* dst; int i;
  if (b < 4096){
    src = x; dst = x16; i = b * 256 + threadIdx.x;
  } else {
    int t = (b - 4096) >> 10;
    i = ((b - 4096) & 1023) * 256 + threadIdx.x;
    src = t == 0 ? Wq : t == 1 ? Wk : t == 2 ? Wv : Wo;
    dst = (t == 3) ? Wo16 : Wcat + (size_t)t * DIM * DIM;
  }
  float4 v = ((const float4*)src)[i];
  ((f16x4*)dst)[i] = (f16x4){(f16)v.x, (f16)v.y, (f16)v.z, (f16)v.w};
}

#define GLOAD16(SRC, DST) __builtin_amdgcn_global_load_lds( \
    (__attribute__((address_space(1))) void*)(SRC), \
    (__attribute__((address_space(3))) void*)(DST), 16, 0, 0)

// theta -> unnormalized exp (shift 10, clamp 11). x->-inf: e1=inf -> sg=0, th=-1.
__device__ __forceinline__ float theta_exp(float v){
  const float e1 = __expf(-v);
  const float sg = 1.f / (1.f + e1);
  const float e2 = e1 * e1;             // e^{-2x}
  const float th = 2.f / (1.f + e2) - 1.f;
  const float theta = 0.5f + 0.2f * sg + 0.15f * th + 0.1f * fmaxf(v, 0.f);
  return __expf(fminf(theta - 10.f, 11.f));
}

// ---------------------------------------------------------------------------
// qkv: 256-thr 128x128 tile, BK=64, single-buffer, 2 barriers/tile. XOR
// swizzle (0 conflicts measured R3-R10). Grid 768 LINEAR with XCD 2D-chunk
// remap (r%8 -> XCD heuristic; perf-only): XCD x gets bm in [(x&3)*8,+8),
// bn in [(x>>2)*12,+12) -> 8 A-panels + 12 B-panels = 5 MB/XCD (first
// co-resident 32 blocks touch 8A+4B = 3 MB, L2-resident).
// col<2048 -> qkcat(+bq/bk), col>=2048 -> vbuf row-major (+bv).
// ---------------------------------------------------------------------------
__global__ __launch_bounds__(256, 3)
void gemm_qkv(const f16* __restrict__ A0, const f16* __restrict__ B0,
              f16* __restrict__ O0, f16* __restrict__ O1,
              const float* __restrict__ c0, const float* __restrict__ c1,
              const float* __restrict__ c2)
{
  __shared__ __align__(16) f16 As[8192];   // 128 x 64 f16
  __shared__ __align__(16) f16 Bs[8192];
  const int tid  = threadIdx.x;
  const int lane = tid & 63;
  const int wid  = tid >> 6;
  const int r = blockIdx.x;
  const int x = r & 7, i5 = r >> 3;        // i5 0..95
  const int bm = (x & 3) * 8 + (i5 & 7);   // 0..31
  const int bn = (x >> 2) * 12 + (i5 >> 3);// 0..23

  const int s_r  = tid >> 3;            // 0..31
  const int s_cb = (tid & 7) ^ (s_r & 7);
  const f16* Ab = A0 + (long)(bm * 128 + s_r) * DIM + s_cb * 8;
  const f16* Bb = B0 + (long)(bn * 128 + s_r) * DIM + s_cb * 8;

  const int l15 = lane & 15, l7 = lane & 7, lhi = lane >> 4;
  const int wrow = (wid >> 1) * 64;
  const int wcol = (wid & 1) * 64;
  const int ar = (wrow + l15) * 64;
  const int br = (wcol + l15) * 64;
  const int cb0 = ((0 + lhi) ^ l7) * 8;
  const int cb1 = ((4 + lhi) ^ l7) * 8;

  f32x4 acc[4][4] = {};

#pragma unroll
  for (int t = 0; t < 16; ++t){
    __syncthreads();
    GLOAD16(Ab + (long)t*64,                  &As[       tid*8]);
    GLOAD16(Ab + (long)t*64 + (long)32 * DIM, &As[2048 + tid*8]);
    GLOAD16(Ab + (long)t*64 + (long)64 * DIM, &As[4096 + tid*8]);
    GLOAD16(Ab + (long)t*64 + (long)96 * DIM, &As[6144 + tid*8]);
    GLOAD16(Bb + (long)t*64,                  &Bs[       tid*8]);
    GLOAD16(Bb + (long)t*64 + (long)32 * DIM, &Bs[2048 + tid*8]);
    GLOAD16(Bb + (long)t*64 + (long)64 * DIM, &Bs[4096 + tid*8]);
    GLOAD16(Bb + (long)t*64 + (long)96 * DIM, &Bs[6144 + tid*8]);
    __syncthreads();
    f16x8 af[4], bf[4];
#pragma unroll
    for (int i = 0; i < 4; i++) af[i] = *(const f16x8*)&As[ar + i * 1024 + cb0];
#pragma unroll
    for (int j = 0; j < 4; j++) bf[j] = *(const f16x8*)&Bs[br + j * 1024 + cb0];
#pragma unroll
    for (int i = 0; i < 4; i++)
#pragma unroll
      for (int j = 0; j < 4; j++)
        acc[i][j] = __builtin_amdgcn_mfma_f32_16x16x32_f16(af[i], bf[j], acc[i][j], 0, 0, 0);
#pragma unroll
    for (int i = 0; i < 4; i++) af[i] = *(const f16x8*)&As[ar + i * 1024 + cb1];
#pragma unroll
    for (int j = 0; j < 4; j++) bf[j] = *(const f16x8*)&Bs[br + j * 1024 + cb1];
#pragma unroll
    for (int i = 0; i < 4; i++)
#pragma unroll
      for (int j = 0; j < 4; j++)
        acc[i][j] = __builtin_amdgcn_mfma_f32_16x16x32_f16(af[i], bf[j], acc[i][j], 0, 0, 0);
  }

  const int cc = l15;
  const int rr = lhi * 4;
#pragma unroll
  for (int i = 0; i < 4; i++)
#pragma unroll
    for (int j = 0; j < 4; j++){
      const int col = bn * 128 + wcol + j * 16 + cc;
      if (col < 2048){
        const float badd = (col < 1024) ? c0[col] : c1[col - 1024];
#pragma unroll
        for (int rq = 0; rq < 4; rq++){
          const int row = bm * 128 + wrow + i * 16 + rr + rq;
          O0[(long)row * 2048 + col] = (f16)(acc[i][j][rq] + badd);
        }
      } else {
        const int dcol = col - 2048;
        const float badd = c2[dcol];
#pragma unroll
        for (int rq = 0; rq < 4; rq++){
          const int row = bm * 128 + wrow + i * 16 + rr + rq;
          O1[(long)row * DIM + dcol] = (f16)(acc[i][j][rq] + badd);
        }
      }
    }
}

// ---------------------------------------------------------------------------
// Merged qk + vWo (128x128 tiles, 512 + 256 = 768 blocks, 3/CU), XCD remap.
// Row sums computed by final kernel (atomic-free).
//   qk (r<512):   P = theta_exp(q@k^T) -> Pbuf (f16).
//   vWo (r>=512): (v@Wo^T)^T -> vWoT[b][e][t] (f16x4 scatter).
// ---------------------------------------------------------------------------
__global__ __launch_bounds__(256, 3)
void gemm_merged(const f16* __restrict__ qkcat, const f16* __restrict__ vbuf,
                 const f16* __restrict__ Wo16,
                 f16* __restrict__ Pbuf, f16* __restrict__ vWoT)
{
  __shared__ __align__(16) f16 As[8192];
  __shared__ __align__(16) f16 Bs[8192];
  const int tid  = threadIdx.x;
  const int lane = tid & 63;
  const int wid  = tid >> 6;
  const int l15 = lane & 15, l7 = lane & 7, lhi = lane >> 4;
  const int s_r  = tid >> 3;
  const int s_cb = (tid & 7) ^ (s_r & 7);
  const int cb0 = ((0 + lhi) ^ l7) * 8;
  const int cb1 = ((4 + lhi) ^ l7) * 8;
  const int cc = l15, rr = lhi * 4;
  const int wrow = (wid >> 1) * 64;
  const int wcol = (wid & 1) * 64;
  const int ar = (wrow + l15) * 64;
  const int br = (wcol + l15) * 64;
  const int r = blockIdx.x;

  if (r < 512){
    // ---------------- qk path: 128x128, ld 2048 ----------------
    const int x = r & 7, i5 = r >> 3;
    const int bz = x >> 2;
    const int bn = (x & 3) * 4 + (i5 & 3);
    const int bm = i5 >> 2;
    const f16* Ab = qkcat + (long)bz * SEQ * 2048 + (long)(bm * 128 + s_r) * 2048 + s_cb * 8;
    const f16* Bb = qkcat + DIM + (long)bz * SEQ * 2048 + (long)(bn * 128 + s_r) * 2048 + s_cb * 8;

    f32x4 acc[4][4] = {};

#pragma unroll
    for (int t = 0; t < 16; ++t){
      __syncthreads();
      GLOAD16(Ab + (long)t*64,                   &As[       tid*8]);
      GLOAD16(Ab + (long)t*64 + (long)32 * 2048, &As[2048 + tid*8]);
      GLOAD16(Ab + (long)t*64 + (long)64 * 2048, &As[4096 + tid*8]);
      GLOAD16(Ab + (long)t*64 + (long)96 * 2048, &As[6144 + tid*8]);
      GLOAD16(Bb + (long)t*64,                   &Bs[       tid*8]);
      GLOAD16(Bb + (long)t*64 + (long)32 * 2048, &Bs[2048 + tid*8]);
      GLOAD16(Bb + (long)t*64 + (long)64 * 2048, &Bs[4096 + tid*8]);
      GLOAD16(Bb + (long)t*64 + (long)96 * 2048, &Bs[6144 + tid*8]);
      __syncthreads();
      f16x8 af[4], bf[4];
#pragma unroll
      for (int i = 0; i < 4; i++) af[i] = *(const f16x8*)&As[ar + i * 1024 + cb0];
#pragma unroll
      for (int j = 0; j < 4; j++) bf[j] = *(const f16x8*)&Bs[br + j * 1024 + cb0];
#pragma unroll
      for (int i = 0; i < 4; i++)
#pragma unroll
        for (int j = 0; j < 4; j++)
          acc[i][j] = __builtin_amdgcn_mfma_f32_16x16x32_f16(af[i], bf[j], acc[i][j], 0, 0, 0);
#pragma unroll
      for (int i = 0; i < 4; i++) af[i] = *(const f16x8*)&As[ar + i * 1024 + cb1];
#pragma unroll
      for (int j = 0; j < 4; j++) bf[j] = *(const f16x8*)&Bs[br + j * 1024 + cb1];
#pragma unroll
      for (int i = 0; i < 4; i++)
#pragma unroll
        for (int j = 0; j < 4; j++)
          acc[i][j] = __builtin_amdgcn_mfma_f32_16x16x32_f16(af[i], bf[j], acc[i][j], 0, 0, 0);
    }

#pragma unroll
    for (int i = 0; i < 4; i++)
#pragma unroll
      for (int rq = 0; rq < 4; rq++){
        const int row = bm * 128 + wrow + i * 16 + rr + rq;
#pragma unroll
        for (int j = 0; j < 4; j++){
          const int col = bn * 128 + wcol + j * 16 + cc;
          Pbuf[(long)bz * SEQ * SEQ + (long)row * SEQ + col] = (f16)theta_exp(acc[i][j][rq]);
        }
      }
  } else {
    // ---------------- vWo path: 128x128, ld 1024 ----------------
    const int rr2 = r - 512;
    const int x = rr2 & 7, i5 = rr2 >> 3;
    const int bz = x >> 2;
    const int bn = (x & 3) * 2 + (i5 & 1);
    const int bm = i5 >> 1;
    const f16* Ab = vbuf + (long)bz * SEQ * DIM + (long)(bm * 128 + s_r) * DIM + s_cb * 8;
    const f16* Bb = Wo16 + (long)(bn * 128 + s_r) * DIM + s_cb * 8;

    f32x4 acc[4][4] = {};

#pragma unroll
    for (int t = 0; t < 16; ++t){
      __syncthreads();
      GLOAD16(Ab + (long)t*64,                  &As[       tid*8]);
      GLOAD16(Ab + (long)t*64 + (long)32 * DIM, &As[2048 + tid*8]);
      GLOAD16(Ab + (long)t*64 + (long)64 * DIM, &As[4096 + tid*8]);
      GLOAD16(Ab + (long)t*64 + (long)96 * DIM, &As[6144 + tid*8]);
      GLOAD16(Bb + (long)t*64,                  &Bs[       tid*8]);
      GLOAD16(Bb + (long)t*64 + (long)32 * DIM, &Bs[2048 + tid*8]);
      GLOAD16(Bb + (long)t*64 + (long)64 * DIM, &Bs[4096 + tid*8]);
      GLOAD16(Bb + (long)t*64 + (long)96 * DIM, &Bs[6144 + tid*8]);
      __syncthreads();
      f16x8 af[4], bf[4];
#pragma unroll
      for (int i = 0; i < 4; i++) af[i] = *(const f16x8*)&As[ar + i * 1024 + cb0];
#pragma unroll
      for (int j = 0; j < 4; j++) bf[j] = *(const f16x8*)&Bs[br + j * 1024 + cb0];
#pragma unroll
      for (int i = 0; i < 4; i++)
#pragma unroll
        for (int j = 0; j < 4; j++)
          acc[i][j] = __builtin_amdgcn_mfma_f32_16x16x32_f16(af[i], bf[j], acc[i][j], 0, 0, 0);
#pragma unroll
      for (int i = 0; i < 4; i++) af[i] = *(const f16x8*)&As[ar + i * 1024 + cb1];
#pragma unroll
      for (int j = 0; j < 4; j++) bf[j] = *(const f16x8*)&Bs[br + j * 1024 + cb1];
#pragma unroll
      for (int i = 0; i < 4; i++)
#pragma unroll
        for (int j = 0; j < 4; j++)
          acc[i][j] = __builtin_amdgcn_mfma_f32_16x16x32_f16(af[i], bf[j], acc[i][j], 0, 0, 0);
    }

#pragma unroll
    for (int i = 0; i < 4; i++)
#pragma unroll
      for (int j = 0; j < 4; j++){
        const int col = bn * 128 + wcol + j * 16 + cc;       // e
        const int row0 = bm * 128 + wrow + i * 16 + rr;      // t (4 consecutive)
        f16x4 pk = {(f16)acc[i][j][0], (f16)acc[i][j][1],
                    (f16)acc[i][j][2], (f16)acc[i][j][3]};
        *(f16x4*)&vWoT[(long)bz * DIM * SEQ + (long)col * SEQ + row0] = pk;
      }
  }
}

// ---------------------------------------------------------------------------
// Final split-K=2 partials (grid (16,8,4) = 1024 blocks, 4/CU, plain stores)
// + atomic-free row sums (R10-proven): even waves sum af P-fragments across
// the K loop; 2 shuffles reduce over lhi; bn==0 blocks store
// rowsum[kh*MTOT + bz*SEQ + row].
// ---------------------------------------------------------------------------
__global__ __launch_bounds__(256, 4)
void gemm_final(const f16* __restrict__ Pb, const f16* __restrict__ Vw,
                float* __restrict__ psum, float* __restrict__ rowsum)
{
  __shared__ __align__(16) f16 As[8192];
  __shared__ __align__(16) f16 Bs[8192];
  const int tid  = threadIdx.x;
  const int lane = tid & 63;
  const int wid  = tid >> 6;
  const int bm = blockIdx.x, bn = blockIdx.y;
  const int bz = blockIdx.z >> 1, kh = blockIdx.z & 1;

  const f16* Ag = Pb + (long)bz * SEQ * SEQ + (long)kh * 1024;
  const f16* Bg = Vw + (long)bz * DIM * SEQ + (long)kh * 1024;

  const int s_r  = tid >> 3;
  const int s_cb = (tid & 7) ^ (s_r & 7);
  const f16* Ab = Ag + (long)(bm * 128 + s_r) * 2048 + s_cb * 8;
  const f16* Bb = Bg + (long)(bn * 128 + s_r) * 2048 + s_cb * 8;

  const int l15 = lane & 15, l7 = lane & 7, lhi = lane >> 4;
  const int wrow = (wid >> 1) * 64;
  const int wcol = (wid & 1) * 64;
  const int ar = (wrow + l15) * 64;
  const int br = (wcol + l15) * 64;
  const int cb0 = ((0 + lhi) ^ l7) * 8;
  const int cb1 = ((4 + lhi) ^ l7) * 8;
  const bool do_rs = ((wid & 1) == 0);

  f32x4 acc[4][4] = {};
  float rsum[4] = {0.f, 0.f, 0.f, 0.f};

#pragma unroll
  for (int t = 0; t < 16; ++t){
    __syncthreads();
    GLOAD16(Ab + (long)t*64,                   &As[       tid*8]);
    GLOAD16(Ab + (long)t*64 + (long)32 * 2048, &As[2048 + tid*8]);
    GLOAD16(Ab + (long)t*64 + (long)64 * 2048, &As[4096 + tid*8]);
    GLOAD16(Ab + (long)t*64 + (long)96 * 2048, &As[6144 + tid*8]);
    GLOAD16(Bb + (long)t*64,                   &Bs[       tid*8]);
    GLOAD16(Bb + (long)t*64 + (long)32 * 2048, &Bs[2048 + tid*8]);
    GLOAD16(Bb + (long)t*64 + (long)64 * 2048, &Bs[4096 + tid*8]);
    GLOAD16(Bb + (long)t*64 + (long)96 * 2048, &Bs[6144 + tid*8]);
    __syncthreads();
    f16x8 af[4], bf[4];
#pragma unroll
    for (int i = 0; i < 4; i++) af[i] = *(const f16x8*)&As[ar + i * 1024 + cb0];
#pragma unroll
    for (int j = 0; j < 4; j++) bf[j] = *(const f16x8*)&Bs[br + j * 1024 + cb0];
#pragma unroll
    for (int i = 0; i < 4; i++)
#pragma unroll
      for (int j = 0; j < 4; j++)
        acc[i][j] = __builtin_amdgcn_mfma_f32_16x16x32_f16(af[i], bf[j], acc[i][j], 0, 0, 0);
    if (do_rs){
#pragma unroll
      for (int i = 0; i < 4; i++)
#pragma unroll
        for (int e = 0; e < 8; e++) rsum[i] += (float)af[i][e];
    }
#pragma unroll
    for (int i = 0; i < 4; i++) af[i] = *(const f16x8*)&As[ar + i * 1024 + cb1];
#pragma unroll
    for (int j = 0; j < 4; j++) bf[j] = *(const f16x8*)&Bs[br + j * 1024 + cb1];
#pragma unroll
    for (int i = 0; i < 4; i++)
#pragma unroll
      for (int j = 0; j < 4; j++)
        acc[i][j] = __builtin_amdgcn_mfma_f32_16x16x32_f16(af[i], bf[j], acc[i][j], 0, 0, 0);
    if (do_rs){
#pragma unroll
      for (int i = 0; i < 4; i++)
#pragma unroll
        for (int e = 0; e < 8; e++) rsum[i] += (float)af[i][e];
    }
  }

  if (do_rs){
#pragma unroll
    for (int i = 0; i < 4; i++){
      rsum[i] += __shfl_xor(rsum[i], 16, 64);
      rsum[i] += __shfl_xor(rsum[i], 32, 64);
    }
    if (bn == 0 && lane < 16){
#pragma unroll
      for (int i = 0; i < 4; i++)
        rowsum[(long)kh * MTOT + bz * SEQ + bm * 128 + wrow + i * 16 + lane] = rsum[i];
    }
  }

  const int cc = l15;
  const int rr = lhi * 4;
  float* Po = psum + (long)kh * MTOT * DIM + (long)bz * SEQ * DIM;
#pragma unroll
  for (int i = 0; i < 4; i++)
#pragma unroll
    for (int j = 0; j < 4; j++){
      const int col = bn * 128 + wcol + j * 16 + cc;
#pragma unroll
      for (int r = 0; r < 4; r++){
        const int row = bm * 128 + wrow + i * 16 + rr + r;
        Po[(long)row * DIM + col] = acc[i][j][r];
      }
    }
}

// out = (psum0 + psum1) / (rs0 + rs1) + bo[col], fp32, float4-vectorized.
__global__ __launch_bounds__(256)
void combine_kernel(const float* __restrict__ psum, const float* __restrict__ rowsum,
                    const float* __restrict__ bo, float* __restrict__ out)
{
  const long i = (long)blockIdx.x * 256 + threadIdx.x;   // float4 index
  const int row = (int)(i >> 8);                         // global row 0..4095
  const int c4  = (int)(i & 255);
  float4 a = ((const float4*)psum)[i];
  float4 b = ((const float4*)psum)[i + (long)MTOT * DIM / 4];
  float4 bb = ((const float4*)bo)[c4];
  const float inv = 1.f / (rowsum[row] + rowsum[MTOT + row]);
  float4 o;
  o.x = (a.x + b.x) * inv + bb.x;
  o.y = (a.y + b.y) * inv + bb.y;
  o.z = (a.z + b.z) * inv + bb.z;
  o.w = (a.w + b.w) * inv + bb.w;
  ((float4*)out)[i] = o;
}

extern "C" void kernel_launch(void* const* d_in, const int* in_sizes, int n_in,
                              void* d_out, int out_size, void* d_ws, size_t ws_size,
                              hipStream_t stream){
  const float* x  = (const float*)d_in[0];
  const float* Wq = (const float*)d_in[1];
  const float* bq = (const float*)d_in[2];
  const float* Wk = (const float*)d_in[3];
  const float* bk = (const float*)d_in[4];
  const float* Wv = (const float*)d_in[5];
  const float* bv = (const float*)d_in[6];
  const float* Wo = (const float*)d_in[7];
  const float* bo = (const float*)d_in[8];
  float* out = (float*)d_out;

  char* ws = (char*)d_ws;
  size_t off = 0;
  auto alloc = [&](size_t bytes) -> char* {
    char* p = ws + off; off += (bytes + 255) & ~(size_t)255; return p;
  };

  f16* x16     = (f16*)alloc(2ull * MTOT * DIM);          // 8 MB
  f16* Wcat    = (f16*)alloc(2ull * 3 * DIM * DIM);       // 6 MB  [Wq;Wk;Wv]
  f16* Wo16    = (f16*)alloc(2ull * DIM * DIM);           // 2 MB
  f16* qkcat   = (f16*)alloc(2ull * MTOT * 2 * DIM);      // 16 MB [q|k] per row
  f16* vbuf    = (f16*)alloc(2ull * MTOT * DIM);          // 8 MB  v row-major
  f16* Pbuf    = (f16*)alloc(2ull * NBATCH * SEQ * SEQ);  // 16 MB unnormalized exp
  f16* vWoT    = (f16*)alloc(2ull * NBATCH * DIM * SEQ);  // 8 MB  (v@Wo^T)^T [b][e][t]
  float* psum  = (float*)alloc(4ull * 2 * MTOT * DIM);    // 32 MB split-K partials
  float* rowsm = (float*)alloc(4ull * 2 * MTOT);          // 32 KB partial row sums

  if (off > ws_size){
    fill_kernel<<<(out_size + 255) / 256, 256, 0, stream>>>(out, 12345.0f, out_size);
    return;
  }

  cvt_all<<<8192, 256, 0, stream>>>(x, Wq, Wk, Wv, Wo, x16, Wcat, Wo16);

  // fused [q|k|v] = x @ [Wq;Wk;Wv]^T + bias  (768 blocks, XCD 2D-chunk remap)
  gemm_qkv<<<768, 256, 0, stream>>>(x16, Wcat, qkcat, vbuf, bq, bk, bv);

  // merged: qk->P [0..511] and vWo^T [512..767], XCD-remapped, 3/CU
  gemm_merged<<<768, 256, 0, stream>>>(qkcat, vbuf, Wo16, Pbuf, vWoT);

  // split-K=2 partials + atomic-free row sums (grid 16x8x4 = 1024, 4/CU)
  gemm_final<<<dim3(SEQ / 128, DIM / 128, 2 * NBATCH), 256, 0, stream>>>(
      Pbuf, vWoT, psum, rowsm);

  // out = (p0+p1)/(rs0+rs1) + bo  (4096 blocks, float4)
  combine_kernel<<<MTOT * DIM / 4 / 256, 256, 0, stream>>>(psum, rowsm, bo, out);
}

// Round 13
// 117.279 us; speedup vs baseline: 1.5220x; 1.0204x over previous
//
#include <hip/hip_runtime.h>
#include <hip/hip_fp16.h>
#include <stdint.h>

typedef _Float16 f16;
typedef __attribute__((ext_vector_type(8))) _Float16 f16x8;
typedef __attribute__((ext_vector_type(4))) _Float16 f16x4;
typedef __attribute__((ext_vector_type(4))) float f32x4;

#define SEQ 2048
#define DIM 1024
#define NBATCH 2
#define MTOT 4096  // NBATCH*SEQ

__global__ void fill_kernel(float* p, float v, int n){
  int i = blockIdx.x * 256 + threadIdx.x;
  if (i < n) p[i] = v;
}

// fp32->fp16 converts: blocks 0..4095 -> x, 4096..8191 -> weights.
__global__ void cvt_all(const float* __restrict__ x, const float* __restrict__ Wq,
                        const float* __restrict__ Wk, const float* __restrict__ Wv,
                        const float* __restrict__ Wo,
                        f16* __restrict__ x16, f16* __restrict__ Wcat, f16* __restrict__ Wo16){
  int b = blockIdx.x;
  const float* src; f16* dst; int i;
  if (b < 4096){
    src = x; dst = x16; i = b * 256 + threadIdx.x;
  } else {
    int t = (b - 4096) >> 10;
    i = ((b - 4096) & 1023) * 256 + threadIdx.x;
    src = t == 0 ? Wq : t == 1 ? Wk : t == 2 ? Wv : Wo;
    dst = (t == 3) ? Wo16 : Wcat + (size_t)t * DIM * DIM;
  }
  float4 v = ((const float4*)src)[i];
  ((f16x4*)dst)[i] = (f16x4){(f16)v.x, (f16)v.y, (f16)v.z, (f16)v.w};
}

#define GLOAD16(SRC, DST) __builtin_amdgcn_global_load_lds( \
    (__attribute__((address_space(1))) void*)(SRC), \
    (__attribute__((address_space(3))) void*)(DST), 16, 0, 0)

// theta -> unnormalized exp (shift 10, clamp 11). x->-inf: e1=inf -> sg=0, th=-1.
// P in [e^-9.65, e^11]; e^-9.65 = 6.4e-5 >= f16 min normal (by design of shift 10).
__device__ __forceinline__ float theta_exp(float v){
  const float e1 = __expf(-v);
  const float sg = 1.f / (1.f + e1);
  const float e2 = e1 * e1;             // e^{-2x}
  const float th = 2.f / (1.f + e2) - 1.f;
  const float theta = 0.5f + 0.2f * sg + 0.15f * th + 0.1f * fmaxf(v, 0.f);
  return __expf(fminf(theta - 10.f, 11.f));
}

// ---------------------------------------------------------------------------
// qkv: 256-thr 128x128 tile, BK=64, single-buffer, 2 barriers/tile. XOR
// swizzle (0 conflicts measured R3-R10). Grid 768 LINEAR with XCD 2D-chunk
// remap: XCD x gets bm in [(x&3)*8,+8), bn in [(x>>2)*12,+12) -> 5 MB/XCD
// working set, L2-resident. col<2048 -> qkcat(+bq/bk), col>=2048 -> vbuf(+bv).
// ---------------------------------------------------------------------------
__global__ __launch_bounds__(256, 3)
void gemm_qkv(const f16* __restrict__ A0, const f16* __restrict__ B0,
              f16* __restrict__ O0, f16* __restrict__ O1,
              const float* __restrict__ c0, const float* __restrict__ c1,
              const float* __restrict__ c2)
{
  __shared__ __align__(16) f16 As[8192];   // 128 x 64 f16
  __shared__ __align__(16) f16 Bs[8192];
  const int tid  = threadIdx.x;
  const int lane = tid & 63;
  const int wid  = tid >> 6;
  const int r = blockIdx.x;
  const int x = r & 7, i5 = r >> 3;        // i5 0..95
  const int bm = (x & 3) * 8 + (i5 & 7);   // 0..31
  const int bn = (x >> 2) * 12 + (i5 >> 3);// 0..23

  const int s_r  = tid >> 3;            // 0..31
  const int s_cb = (tid & 7) ^ (s_r & 7);
  const f16* Ab = A0 + (long)(bm * 128 + s_r) * DIM + s_cb * 8;
  const f16* Bb = B0 + (long)(bn * 128 + s_r) * DIM + s_cb * 8;

  const int l15 = lane & 15, l7 = lane & 7, lhi = lane >> 4;
  const int wrow = (wid >> 1) * 64;
  const int wcol = (wid & 1) * 64;
  const int ar = (wrow + l15) * 64;
  const int br = (wcol + l15) * 64;
  const int cb0 = ((0 + lhi) ^ l7) * 8;
  const int cb1 = ((4 + lhi) ^ l7) * 8;

  f32x4 acc[4][4] = {};

#pragma unroll
  for (int t = 0; t < 16; ++t){
    __syncthreads();
    GLOAD16(Ab + (long)t*64,                  &As[       tid*8]);
    GLOAD16(Ab + (long)t*64 + (long)32 * DIM, &As[2048 + tid*8]);
    GLOAD16(Ab + (long)t*64 + (long)64 * DIM, &As[4096 + tid*8]);
    GLOAD16(Ab + (long)t*64 + (long)96 * DIM, &As[6144 + tid*8]);
    GLOAD16(Bb + (long)t*64,                  &Bs[       tid*8]);
    GLOAD16(Bb + (long)t*64 + (long)32 * DIM, &Bs[2048 + tid*8]);
    GLOAD16(Bb + (long)t*64 + (long)64 * DIM, &Bs[4096 + tid*8]);
    GLOAD16(Bb + (long)t*64 + (long)96 * DIM, &Bs[6144 + tid*8]);
    __syncthreads();
    f16x8 af[4], bf[4];
#pragma unroll
    for (int i = 0; i < 4; i++) af[i] = *(const f16x8*)&As[ar + i * 1024 + cb0];
#pragma unroll
    for (int j = 0; j < 4; j++) bf[j] = *(const f16x8*)&Bs[br + j * 1024 + cb0];
#pragma unroll
    for (int i = 0; i < 4; i++)
#pragma unroll
      for (int j = 0; j < 4; j++)
        acc[i][j] = __builtin_amdgcn_mfma_f32_16x16x32_f16(af[i], bf[j], acc[i][j], 0, 0, 0);
#pragma unroll
    for (int i = 0; i < 4; i++) af[i] = *(const f16x8*)&As[ar + i * 1024 + cb1];
#pragma unroll
    for (int j = 0; j < 4; j++) bf[j] = *(const f16x8*)&Bs[br + j * 1024 + cb1];
#pragma unroll
    for (int i = 0; i < 4; i++)
#pragma unroll
      for (int j = 0; j < 4; j++)
        acc[i][j] = __builtin_amdgcn_mfma_f32_16x16x32_f16(af[i], bf[j], acc[i][j], 0, 0, 0);
  }

  const int cc = l15;
  const int rr = lhi * 4;
#pragma unroll
  for (int i = 0; i < 4; i++)
#pragma unroll
    for (int j = 0; j < 4; j++){
      const int col = bn * 128 + wcol + j * 16 + cc;
      if (col < 2048){
        const float badd = (col < 1024) ? c0[col] : c1[col - 1024];
#pragma unroll
        for (int rq = 0; rq < 4; rq++){
          const int row = bm * 128 + wrow + i * 16 + rr + rq;
          O0[(long)row * 2048 + col] = (f16)(acc[i][j][rq] + badd);
        }
      } else {
        const int dcol = col - 2048;
        const float badd = c2[dcol];
#pragma unroll
        for (int rq = 0; rq < 4; rq++){
          const int row = bm * 128 + wrow + i * 16 + rr + rq;
          O1[(long)row * DIM + dcol] = (f16)(acc[i][j][rq] + badd);
        }
      }
    }
}

// ---------------------------------------------------------------------------
// Merged qk + vWo (128x128 tiles, 512 + 256 = 768 blocks, 3/CU), XCD remap.
// Row sums computed by final kernel (atomic-free).
//   qk (r<512):   P = theta_exp(q@k^T) -> Pbuf (f16).
//   vWo (r>=512): (v@Wo^T)^T -> vWoT[b][e][t] (f16x4 scatter).
// ---------------------------------------------------------------------------
__global__ __launch_bounds__(256, 3)
void gemm_merged(const f16* __restrict__ qkcat, const f16* __restrict__ vbuf,
                 const f16* __restrict__ Wo16,
                 f16* __restrict__ Pbuf, f16* __restrict__ vWoT)
{
  __shared__ __align__(16) f16 As[8192];
  __shared__ __align__(16) f16 Bs[8192];
  const int tid  = threadIdx.x;
  const int lane = tid & 63;
  const int wid  = tid >> 6;
  const int l15 = lane & 15, l7 = lane & 7, lhi = lane >> 4;
  const int s_r  = tid >> 3;
  const int s_cb = (tid & 7) ^ (s_r & 7);
  const int cb0 = ((0 + lhi) ^ l7) * 8;
  const int cb1 = ((4 + lhi) ^ l7) * 8;
  const int cc = l15, rr = lhi * 4;
  const int wrow = (wid >> 1) * 64;
  const int wcol = (wid & 1) * 64;
  const int ar = (wrow + l15) * 64;
  const int br = (wcol + l15) * 64;
  const int r = blockIdx.x;

  if (r < 512){
    // ---------------- qk path: 128x128, ld 2048 ----------------
    const int x = r & 7, i5 = r >> 3;
    const int bz = x >> 2;
    const int bn = (x & 3) * 4 + (i5 & 3);
    const int bm = i5 >> 2;
    const f16* Ab = qkcat + (long)bz * SEQ * 2048 + (long)(bm * 128 + s_r) * 2048 + s_cb * 8;
    const f16* Bb = qkcat + DIM + (long)bz * SEQ * 2048 + (long)(bn * 128 + s_r) * 2048 + s_cb * 8;

    f32x4 acc[4][4] = {};

#pragma unroll
    for (int t = 0; t < 16; ++t){
      __syncthreads();
      GLOAD16(Ab + (long)t*64,                   &As[       tid*8]);
      GLOAD16(Ab + (long)t*64 + (long)32 * 2048, &As[2048 + tid*8]);
      GLOAD16(Ab + (long)t*64 + (long)64 * 2048, &As[4096 + tid*8]);
      GLOAD16(Ab + (long)t*64 + (long)96 * 2048, &As[6144 + tid*8]);
      GLOAD16(Bb + (long)t*64,                   &Bs[       tid*8]);
      GLOAD16(Bb + (long)t*64 + (long)32 * 2048, &Bs[2048 + tid*8]);
      GLOAD16(Bb + (long)t*64 + (long)64 * 2048, &Bs[4096 + tid*8]);
      GLOAD16(Bb + (long)t*64 + (long)96 * 2048, &Bs[6144 + tid*8]);
      __syncthreads();
      f16x8 af[4], bf[4];
#pragma unroll
      for (int i = 0; i < 4; i++) af[i] = *(const f16x8*)&As[ar + i * 1024 + cb0];
#pragma unroll
      for (int j = 0; j < 4; j++) bf[j] = *(const f16x8*)&Bs[br + j * 1024 + cb0];
#pragma unroll
      for (int i = 0; i < 4; i++)
#pragma unroll
        for (int j = 0; j < 4; j++)
          acc[i][j] = __builtin_amdgcn_mfma_f32_16x16x32_f16(af[i], bf[j], acc[i][j], 0, 0, 0);
#pragma unroll
      for (int i = 0; i < 4; i++) af[i] = *(const f16x8*)&As[ar + i * 1024 + cb1];
#pragma unroll
      for (int j = 0; j < 4; j++) bf[j] = *(const f16x8*)&Bs[br + j * 1024 + cb1];
#pragma unroll
      for (int i = 0; i < 4; i++)
#pragma unroll
        for (int j = 0; j < 4; j++)
          acc[i][j] = __builtin_amdgcn_mfma_f32_16x16x32_f16(af[i], bf[j], acc[i][j], 0, 0, 0);
    }

#pragma unroll
    for (int i = 0; i < 4; i++)
#pragma unroll
      for (int rq = 0; rq < 4; rq++){
        const int row = bm * 128 + wrow + i * 16 + rr + rq;
#pragma unroll
        for (int j = 0; j < 4; j++){
          const int col = bn * 128 + wcol + j * 16 + cc;
          Pbuf[(long)bz * SEQ * SEQ + (long)row * SEQ + col] = (f16)theta_exp(acc[i][j][rq]);
        }
      }
  } else {
    // ---------------- vWo path: 128x128, ld 1024 ----------------
    const int rr2 = r - 512;
    const int x = rr2 & 7, i5 = rr2 >> 3;
    const int bz = x >> 2;
    const int bn = (x & 3) * 2 + (i5 & 1);
    const int bm = i5 >> 1;
    const f16* Ab = vbuf + (long)bz * SEQ * DIM + (long)(bm * 128 + s_r) * DIM + s_cb * 8;
    const f16* Bb = Wo16 + (long)(bn * 128 + s_r) * DIM + s_cb * 8;

    f32x4 acc[4][4] = {};

#pragma unroll
    for (int t = 0; t < 16; ++t){
      __syncthreads();
      GLOAD16(Ab + (long)t*64,                  &As[       tid*8]);
      GLOAD16(Ab + (long)t*64 + (long)32 * DIM, &As[2048 + tid*8]);
      GLOAD16(Ab + (long)t*64 + (long)64 * DIM, &As[4096 + tid*8]);
      GLOAD16(Ab + (long)t*64 + (long)96 * DIM, &As[6144 + tid*8]);
      GLOAD16(Bb + (long)t*64,                  &Bs[       tid*8]);
      GLOAD16(Bb + (long)t*64 + (long)32 * DIM, &Bs[2048 + tid*8]);
      GLOAD16(Bb + (long)t*64 + (long)64 * DIM, &Bs[4096 + tid*8]);
      GLOAD16(Bb + (long)t*64 + (long)96 * DIM, &Bs[6144 + tid*8]);
      __syncthreads();
      f16x8 af[4], bf[4];
#pragma unroll
      for (int i = 0; i < 4; i++) af[i] = *(const f16x8*)&As[ar + i * 1024 + cb0];
#pragma unroll
      for (int j = 0; j < 4; j++) bf[j] = *(const f16x8*)&Bs[br + j * 1024 + cb0];
#pragma unroll
      for (int i = 0; i < 4; i++)
#pragma unroll
        for (int j = 0; j < 4; j++)
          acc[i][j] = __builtin_amdgcn_mfma_f32_16x16x32_f16(af[i], bf[j], acc[i][j], 0, 0, 0);
#pragma unroll
      for (int i = 0; i < 4; i++) af[i] = *(const f16x8*)&As[ar + i * 1024 + cb1];
#pragma unroll
      for (int j = 0; j < 4; j++) bf[j] = *(const f16x8*)&Bs[br + j * 1024 + cb1];
#pragma unroll
      for (int i = 0; i < 4; i++)
#pragma unroll
        for (int j = 0; j < 4; j++)
          acc[i][j] = __builtin_amdgcn_mfma_f32_16x16x32_f16(af[i], bf[j], acc[i][j], 0, 0, 0);
    }

#pragma unroll
    for (int i = 0; i < 4; i++)
#pragma unroll
      for (int j = 0; j < 4; j++){
        const int col = bn * 128 + wcol + j * 16 + cc;       // e
        const int row0 = bm * 128 + wrow + i * 16 + rr;      // t (4 consecutive)
        f16x4 pk = {(f16)acc[i][j][0], (f16)acc[i][j][1],
                    (f16)acc[i][j][2], (f16)acc[i][j][3]};
        *(f16x4*)&vWoT[(long)bz * DIM * SEQ + (long)col * SEQ + row0] = pk;
      }
  }
}

// ---------------------------------------------------------------------------
// Final split-K=2 partials (grid (16,8,4) = 1024 blocks, 4/CU, plain stores)
// + atomic-free row sums (R10-proven). psum now FP16: |psum| = O(1-10)
// (P in [6.4e-5, e^1.1], |vWo| ~ N(0,1)), f16 range/precision ample;
// halves psum write traffic (33.5 -> 16.8 MB).
// ---------------------------------------------------------------------------
__global__ __launch_bounds__(256, 4)
void gemm_final(const f16* __restrict__ Pb, const f16* __restrict__ Vw,
                f16* __restrict__ psum, float* __restrict__ rowsum)
{
  __shared__ __align__(16) f16 As[8192];
  __shared__ __align__(16) f16 Bs[8192];
  const int tid  = threadIdx.x;
  const int lane = tid & 63;
  const int wid  = tid >> 6;
  const int bm = blockIdx.x, bn = blockIdx.y;
  const int bz = blockIdx.z >> 1, kh = blockIdx.z & 1;

  const f16* Ag = Pb + (long)bz * SEQ * SEQ + (long)kh * 1024;
  const f16* Bg = Vw + (long)bz * DIM * SEQ + (long)kh * 1024;

  const int s_r  = tid >> 3;
  const int s_cb = (tid & 7) ^ (s_r & 7);
  const f16* Ab = Ag + (long)(bm * 128 + s_r) * 2048 + s_cb * 8;
  const f16* Bb = Bg + (long)(bn * 128 + s_r) * 2048 + s_cb * 8;

  const int l15 = lane & 15, l7 = lane & 7, lhi = lane >> 4;
  const int wrow = (wid >> 1) * 64;
  const int wcol = (wid & 1) * 64;
  const int ar = (wrow + l15) * 64;
  const int br = (wcol + l15) * 64;
  const int cb0 = ((0 + lhi) ^ l7) * 8;
  const int cb1 = ((4 + lhi) ^ l7) * 8;
  const bool do_rs = ((wid & 1) == 0);

  f32x4 acc[4][4] = {};
  float rsum[4] = {0.f, 0.f, 0.f, 0.f};

#pragma unroll
  for (int t = 0; t < 16; ++t){
    __syncthreads();
    GLOAD16(Ab + (long)t*64,                   &As[       tid*8]);
    GLOAD16(Ab + (long)t*64 + (long)32 * 2048, &As[2048 + tid*8]);
    GLOAD16(Ab + (long)t*64 + (long)64 * 2048, &As[4096 + tid*8]);
    GLOAD16(Ab + (long)t*64 + (long)96 * 2048, &As[6144 + tid*8]);
    GLOAD16(Bb + (long)t*64,                   &Bs[       tid*8]);
    GLOAD16(Bb + (long)t*64 + (long)32 * 2048, &Bs[2048 + tid*8]);
    GLOAD16(Bb + (long)t*64 + (long)64 * 2048, &Bs[4096 + tid*8]);
    GLOAD16(Bb + (long)t*64 + (long)96 * 2048, &Bs[6144 + tid*8]);
    __syncthreads();
    f16x8 af[4], bf[4];
#pragma unroll
    for (int i = 0; i < 4; i++) af[i] = *(const f16x8*)&As[ar + i * 1024 + cb0];
#pragma unroll
    for (int j = 0; j < 4; j++) bf[j] = *(const f16x8*)&Bs[br + j * 1024 + cb0];
#pragma unroll
    for (int i = 0; i < 4; i++)
#pragma unroll
      for (int j = 0; j < 4; j++)
        acc[i][j] = __builtin_amdgcn_mfma_f32_16x16x32_f16(af[i], bf[j], acc[i][j], 0, 0, 0);
    if (do_rs){
#pragma unroll
      for (int i = 0; i < 4; i++)
#pragma unroll
        for (int e = 0; e < 8; e++) rsum[i] += (float)af[i][e];
    }
#pragma unroll
    for (int i = 0; i < 4; i++) af[i] = *(const f16x8*)&As[ar + i * 1024 + cb1];
#pragma unroll
    for (int j = 0; j < 4; j++) bf[j] = *(const f16x8*)&Bs[br + j * 1024 + cb1];
#pragma unroll
    for (int i = 0; i < 4; i++)
#pragma unroll
      for (int j = 0; j < 4; j++)
        acc[i][j] = __builtin_amdgcn_mfma_f32_16x16x32_f16(af[i], bf[j], acc[i][j], 0, 0, 0);
    if (do_rs){
#pragma unroll
      for (int i = 0; i < 4; i++)
#pragma unroll
        for (int e = 0; e < 8; e++) rsum[i] += (float)af[i][e];
    }
  }

  if (do_rs){
#pragma unroll
    for (int i = 0; i < 4; i++){
      rsum[i] += __shfl_xor(rsum[i], 16, 64);
      rsum[i] += __shfl_xor(rsum[i], 32, 64);
    }
    if (bn == 0 && lane < 16){
#pragma unroll
      for (int i = 0; i < 4; i++)
        rowsum[(long)kh * MTOT + bz * SEQ + bm * 128 + wrow + i * 16 + lane] = rsum[i];
    }
  }

  const int cc = l15;
  const int rr = lhi * 4;
  f16* Po = psum + (long)kh * MTOT * DIM + (long)bz * SEQ * DIM;
#pragma unroll
  for (int i = 0; i < 4; i++)
#pragma unroll
    for (int j = 0; j < 4; j++){
      const int col = bn * 128 + wcol + j * 16 + cc;
#pragma unroll
      for (int r = 0; r < 4; r++){
        const int row = bm * 128 + wrow + i * 16 + rr + r;
        Po[(long)row * DIM + col] = (f16)acc[i][j][r];
      }
    }
}

// out = (psum0 + psum1) / (rs0 + rs1) + bo[col], psum f16, out fp32.
__global__ __launch_bounds__(256)
void combine_kernel(const f16* __restrict__ psum, const float* __restrict__ rowsum,
                    const float* __restrict__ bo, float* __restrict__ out)
{
  const long i = (long)blockIdx.x * 256 + threadIdx.x;   // 4-elem group index
  const int row = (int)(i >> 8);                         // global row 0..4095
  const int c4  = (int)(i & 255);
  f16x4 a = ((const f16x4*)psum)[i];
  f16x4 b = ((const f16x4*)(psum + (long)MTOT * DIM))[i];
  float4 bb = ((const float4*)bo)[c4];
  const float inv = 1.f / (rowsum[row] + rowsum[MTOT + row]);
  float4 o;
  o.x = ((float)a[0] + (float)b[0]) * inv + bb.x;
  o.y = ((float)a[1] + (float)b[1]) * inv + bb.y;
  o.z = ((float)a[2] + (float)b[2]) * inv + bb.z;
  o.w = ((float)a[3] + (float)b[3]) * inv + bb.w;
  ((float4*)out)[i] = o;
}

extern "C" void kernel_launch(void* const* d_in, const int* in_sizes, int n_in,
                              void* d_out, int out_size, void* d_ws, size_t ws_size,
                              hipStream_t stream){
  const float* x  = (const float*)d_in[0];
  const float* Wq = (const float*)d_in[1];
  const float* bq = (const float*)d_in[2];
  const float* Wk = (const float*)d_in[3];
  const float* bk = (const float*)d_in[4];
  const float* Wv = (const float*)d_in[5];
  const float* bv = (const float*)d_in[6];
  const float* Wo = (const float*)d_in[7];
  const float* bo = (const float*)d_in[8];
  float* out = (float*)d_out;

  char* ws = (char*)d_ws;
  size_t off = 0;
  auto alloc = [&](size_t bytes) -> char* {
    char* p = ws + off; off += (bytes + 255) & ~(size_t)255; return p;
  };

  f16* x16     = (f16*)alloc(2ull * MTOT * DIM);          // 8 MB
  f16* Wcat    = (f16*)alloc(2ull * 3 * DIM * DIM);       // 6 MB  [Wq;Wk;Wv]
  f16* Wo16    = (f16*)alloc(2ull * DIM * DIM);           // 2 MB
  f16* qkcat   = (f16*)alloc(2ull * MTOT * 2 * DIM);      // 16 MB [q|k] per row
  f16* vbuf    = (f16*)alloc(2ull * MTOT * DIM);          // 8 MB  v row-major
  f16* Pbuf    = (f16*)alloc(2ull * NBATCH * SEQ * SEQ);  // 16 MB unnormalized exp
  f16* vWoT    = (f16*)alloc(2ull * NBATCH * DIM * SEQ);  // 8 MB  (v@Wo^T)^T [b][e][t]
  f16* psum    = (f16*)alloc(2ull * 2 * MTOT * DIM);      // 16.8 MB split-K partials (f16)
  float* rowsm = (float*)alloc(4ull * 2 * MTOT);          // 32 KB partial row sums

  if (off > ws_size){
    fill_kernel<<<(out_size + 255) / 256, 256, 0, stream>>>(out, 12345.0f, out_size);
    return;
  }

  cvt_all<<<8192, 256, 0, stream>>>(x, Wq, Wk, Wv, Wo, x16, Wcat, Wo16);

  // fused [q|k|v] = x @ [Wq;Wk;Wv]^T + bias  (768 blocks, XCD 2D-chunk remap)
  gemm_qkv<<<768, 256, 0, stream>>>(x16, Wcat, qkcat, vbuf, bq, bk, bv);

  // merged: qk->P [0..511] and vWo^T [512..767], XCD-remapped, 3/CU
  gemm_merged<<<768, 256, 0, stream>>>(qkcat, vbuf, Wo16, Pbuf, vWoT);

  // split-K=2 f16 partials + atomic-free row sums (grid 16x8x4 = 1024, 4/CU)
  gemm_final<<<dim3(SEQ / 128, DIM / 128, 2 * NBATCH), 256, 0, stream>>>(
      Pbuf, vWoT, psum, rowsm);

  // out = (p0+p1)/(rs0+rs1) + bo  (4096 blocks, f16 reads, float4 writes)
  combine_kernel<<<MTOT * DIM / 4 / 256, 256, 0, stream>>>(psum, rowsm, bo, out);
}

// Round 14
// 116.400 us; speedup vs baseline: 1.5335x; 1.0075x over previous
//
#include <hip/hip_runtime.h>
#include <hip/hip_fp16.h>
#include <stdint.h>

typedef _Float16 f16;
typedef __attribute__((ext_vector_type(8))) _Float16 f16x8;
typedef __attribute__((ext_vector_type(4))) _Float16 f16x4;
typedef __attribute__((ext_vector_type(4))) float f32x4;

#define SEQ 2048
#define DIM 1024
#define NBATCH 2
#define MTOT 4096  // NBATCH*SEQ

__global__ void fill_kernel(float* p, float v, int n){
  int i = blockIdx.x * 256 + threadIdx.x;
  if (i < n) p[i] = v;
}

// fp32->fp16 converts: blocks 0..4095 -> x, 4096..8191 -> weights.
__global__ void cvt_all(const float* __restrict__ x, const float* __restrict__ Wq,
                        const float* __restrict__ Wk, const float* __restrict__ Wv,
                        const float* __restrict__ Wo,
                        f16* __restrict__ x16, f16* __restrict__ Wcat, f16* __restrict__ Wo16){
  int b = blockIdx.x;
  const float* src; f16* dst; int i;
  if (b < 4096){
    src = x; dst = x16; i = b * 256 + threadIdx.x;
  } else {
    int t = (b - 4096) >> 10;
    i = ((b - 4096) & 1023) * 256 + threadIdx.x;
    src = t == 0 ? Wq : t == 1 ? Wk : t == 2 ? Wv : Wo;
    dst = (t == 3) ? Wo16 : Wcat + (size_t)t * DIM * DIM;
  }
  float4 v = ((const float4*)src)[i];
  ((f16x4*)dst)[i] = (f16x4){(f16)v.x, (f16)v.y, (f16)v.z, (f16)v.w};
}

#define GLOAD16(SRC, DST) __builtin_amdgcn_global_load_lds( \
    (__attribute__((address_space(1))) void*)(SRC), \
    (__attribute__((address_space(3))) void*)(DST), 16, 0, 0)

// theta -> unnormalized exp (shift 10, clamp 11). x->-inf: e1=inf -> sg=0, th=-1.
// P in [e^-9.65, e^11]; e^-9.65 = 6.4e-5 >= f16 min normal (by design of shift 10).
__device__ __forceinline__ float theta_exp(float v){
  const float e1 = __expf(-v);
  const float sg = 1.f / (1.f + e1);
  const float e2 = e1 * e1;             // e^{-2x}
  const float th = 2.f / (1.f + e2) - 1.f;
  const float theta = 0.5f + 0.2f * sg + 0.15f * th + 0.1f * fmaxf(v, 0.f);
  return __expf(fminf(theta - 10.f, 11.f));
}

// ---------------------------------------------------------------------------
// qkv: 256-thr 128x128 tile, BK=64, single-buffer, 2 barriers/tile. XOR
// swizzle (0 conflicts measured R3-R13). Grid 768 LINEAR with XCD 2D-chunk
// remap: XCD x gets bm in [(x&3)*8,+8), bn in [(x>>2)*12,+12).
// Epilogue: col<1024 -> qbuf(+bq), col<2048 -> kbuf(+bk), else vbuf(+bv).
// q,k now DE-INTERLEAVED (dense ld=1024 panels) so the qk GEMM's tiles have
// the same L2 density as this kernel's (R14 change).
// ---------------------------------------------------------------------------
__global__ __launch_bounds__(256, 3)
void gemm_qkv(const f16* __restrict__ A0, const f16* __restrict__ B0,
              f16* __restrict__ Oq, f16* __restrict__ Ok, f16* __restrict__ Ov,
              const float* __restrict__ c0, const float* __restrict__ c1,
              const float* __restrict__ c2)
{
  __shared__ __align__(16) f16 As[8192];   // 128 x 64 f16
  __shared__ __align__(16) f16 Bs[8192];
  const int tid  = threadIdx.x;
  const int lane = tid & 63;
  const int wid  = tid >> 6;
  const int r = blockIdx.x;
  const int x = r & 7, i5 = r >> 3;        // i5 0..95
  const int bm = (x & 3) * 8 + (i5 & 7);   // 0..31
  const int bn = (x >> 2) * 12 + (i5 >> 3);// 0..23

  const int s_r  = tid >> 3;            // 0..31
  const int s_cb = (tid & 7) ^ (s_r & 7);
  const f16* Ab = A0 + (long)(bm * 128 + s_r) * DIM + s_cb * 8;
  const f16* Bb = B0 + (long)(bn * 128 + s_r) * DIM + s_cb * 8;

  const int l15 = lane & 15, l7 = lane & 7, lhi = lane >> 4;
  const int wrow = (wid >> 1) * 64;
  const int wcol = (wid & 1) * 64;
  const int ar = (wrow + l15) * 64;
  const int br = (wcol + l15) * 64;
  const int cb0 = ((0 + lhi) ^ l7) * 8;
  const int cb1 = ((4 + lhi) ^ l7) * 8;

  f32x4 acc[4][4] = {};

#pragma unroll
  for (int t = 0; t < 16; ++t){
    __syncthreads();
    GLOAD16(Ab + (long)t*64,                  &As[       tid*8]);
    GLOAD16(Ab + (long)t*64 + (long)32 * DIM, &As[2048 + tid*8]);
    GLOAD16(Ab + (long)t*64 + (long)64 * DIM, &As[4096 + tid*8]);
    GLOAD16(Ab + (long)t*64 + (long)96 * DIM, &As[6144 + tid*8]);
    GLOAD16(Bb + (long)t*64,                  &Bs[       tid*8]);
    GLOAD16(Bb + (long)t*64 + (long)32 * DIM, &Bs[2048 + tid*8]);
    GLOAD16(Bb + (long)t*64 + (long)64 * DIM, &Bs[4096 + tid*8]);
    GLOAD16(Bb + (long)t*64 + (long)96 * DIM, &Bs[6144 + tid*8]);
    __syncthreads();
    f16x8 af[4], bf[4];
#pragma unroll
    for (int i = 0; i < 4; i++) af[i] = *(const f16x8*)&As[ar + i * 1024 + cb0];
#pragma unroll
    for (int j = 0; j < 4; j++) bf[j] = *(const f16x8*)&Bs[br + j * 1024 + cb0];
#pragma unroll
    for (int i = 0; i < 4; i++)
#pragma unroll
      for (int j = 0; j < 4; j++)
        acc[i][j] = __builtin_amdgcn_mfma_f32_16x16x32_f16(af[i], bf[j], acc[i][j], 0, 0, 0);
#pragma unroll
    for (int i = 0; i < 4; i++) af[i] = *(const f16x8*)&As[ar + i * 1024 + cb1];
#pragma unroll
    for (int j = 0; j < 4; j++) bf[j] = *(const f16x8*)&Bs[br + j * 1024 + cb1];
#pragma unroll
    for (int i = 0; i < 4; i++)
#pragma unroll
      for (int j = 0; j < 4; j++)
        acc[i][j] = __builtin_amdgcn_mfma_f32_16x16x32_f16(af[i], bf[j], acc[i][j], 0, 0, 0);
  }

  const int cc = l15;
  const int rr = lhi * 4;
#pragma unroll
  for (int i = 0; i < 4; i++)
#pragma unroll
    for (int j = 0; j < 4; j++){
      const int col = bn * 128 + wcol + j * 16 + cc;
      f16* dst; int dcol; float badd;
      if (col < 1024){       dst = Oq; dcol = col;        badd = c0[dcol]; }
      else if (col < 2048){  dst = Ok; dcol = col - 1024; badd = c1[dcol]; }
      else {                 dst = Ov; dcol = col - 2048; badd = c2[dcol]; }
#pragma unroll
      for (int rq = 0; rq < 4; rq++){
        const int row = bm * 128 + wrow + i * 16 + rr + rq;
        dst[(long)row * DIM + dcol] = (f16)(acc[i][j][rq] + badd);
      }
    }
}

// ---------------------------------------------------------------------------
// Merged qk + vWo (128x128 tiles, 512 + 256 = 768 blocks, 3/CU), XCD remap.
// Both paths now read dense ld=1024 panels. Row sums computed by final kernel.
//   qk (r<512):   P = theta_exp(q@k^T) -> Pbuf (f16).
//   vWo (r>=512): (v@Wo^T)^T -> vWoT[b][e][t] (f16x4 scatter).
// ---------------------------------------------------------------------------
__global__ __launch_bounds__(256, 3)
void gemm_merged(const f16* __restrict__ qbuf, const f16* __restrict__ kbuf,
                 const f16* __restrict__ vbuf, const f16* __restrict__ Wo16,
                 f16* __restrict__ Pbuf, f16* __restrict__ vWoT)
{
  __shared__ __align__(16) f16 As[8192];
  __shared__ __align__(16) f16 Bs[8192];
  const int tid  = threadIdx.x;
  const int lane = tid & 63;
  const int wid  = tid >> 6;
  const int l15 = lane & 15, l7 = lane & 7, lhi = lane >> 4;
  const int s_r  = tid >> 3;
  const int s_cb = (tid & 7) ^ (s_r & 7);
  const int cb0 = ((0 + lhi) ^ l7) * 8;
  const int cb1 = ((4 + lhi) ^ l7) * 8;
  const int cc = l15, rr = lhi * 4;
  const int wrow = (wid >> 1) * 64;
  const int wcol = (wid & 1) * 64;
  const int ar = (wrow + l15) * 64;
  const int br = (wcol + l15) * 64;
  const int r = blockIdx.x;

  const f16 *Ab, *Bb;
  int bm, bn, bz;
  bool isQK;
  if (r < 512){
    isQK = true;
    const int x = r & 7, i5 = r >> 3;
    bz = x >> 2;
    bn = (x & 3) * 4 + (i5 & 3);
    bm = i5 >> 2;
    Ab = qbuf + (long)bz * SEQ * DIM + (long)(bm * 128 + s_r) * DIM + s_cb * 8;
    Bb = kbuf + (long)bz * SEQ * DIM + (long)(bn * 128 + s_r) * DIM + s_cb * 8;
  } else {
    isQK = false;
    const int rr2 = r - 512;
    const int x = rr2 & 7, i5 = rr2 >> 3;
    bz = x >> 2;
    bn = (x & 3) * 2 + (i5 & 1);
    bm = i5 >> 1;
    Ab = vbuf + (long)bz * SEQ * DIM + (long)(bm * 128 + s_r) * DIM + s_cb * 8;
    Bb = Wo16 + (long)(bn * 128 + s_r) * DIM + s_cb * 8;
  }

  f32x4 acc[4][4] = {};

#pragma unroll
  for (int t = 0; t < 16; ++t){
    __syncthreads();
    GLOAD16(Ab + (long)t*64,                  &As[       tid*8]);
    GLOAD16(Ab + (long)t*64 + (long)32 * DIM, &As[2048 + tid*8]);
    GLOAD16(Ab + (long)t*64 + (long)64 * DIM, &As[4096 + tid*8]);
    GLOAD16(Ab + (long)t*64 + (long)96 * DIM, &As[6144 + tid*8]);
    GLOAD16(Bb + (long)t*64,                  &Bs[       tid*8]);
    GLOAD16(Bb + (long)t*64 + (long)32 * DIM, &Bs[2048 + tid*8]);
    GLOAD16(Bb + (long)t*64 + (long)64 * DIM, &Bs[4096 + tid*8]);
    GLOAD16(Bb + (long)t*64 + (long)96 * DIM, &Bs[6144 + tid*8]);
    __syncthreads();
    f16x8 af[4], bf[4];
#pragma unroll
    for (int i = 0; i < 4; i++) af[i] = *(const f16x8*)&As[ar + i * 1024 + cb0];
#pragma unroll
    for (int j = 0; j < 4; j++) bf[j] = *(const f16x8*)&Bs[br + j * 1024 + cb0];
#pragma unroll
    for (int i = 0; i < 4; i++)
#pragma unroll
      for (int j = 0; j < 4; j++)
        acc[i][j] = __builtin_amdgcn_mfma_f32_16x16x32_f16(af[i], bf[j], acc[i][j], 0, 0, 0);
#pragma unroll
    for (int i = 0; i < 4; i++) af[i] = *(const f16x8*)&As[ar + i * 1024 + cb1];
#pragma unroll
    for (int j = 0; j < 4; j++) bf[j] = *(const f16x8*)&Bs[br + j * 1024 + cb1];
#pragma unroll
    for (int i = 0; i < 4; i++)
#pragma unroll
      for (int j = 0; j < 4; j++)
        acc[i][j] = __builtin_amdgcn_mfma_f32_16x16x32_f16(af[i], bf[j], acc[i][j], 0, 0, 0);
  }

  if (isQK){
#pragma unroll
    for (int i = 0; i < 4; i++)
#pragma unroll
      for (int rq = 0; rq < 4; rq++){
        const int row = bm * 128 + wrow + i * 16 + rr + rq;
#pragma unroll
        for (int j = 0; j < 4; j++){
          const int col = bn * 128 + wcol + j * 16 + cc;
          Pbuf[(long)bz * SEQ * SEQ + (long)row * SEQ + col] = (f16)theta_exp(acc[i][j][rq]);
        }
      }
  } else {
#pragma unroll
    for (int i = 0; i < 4; i++)
#pragma unroll
      for (int j = 0; j < 4; j++){
        const int col = bn * 128 + wcol + j * 16 + cc;       // e
        const int row0 = bm * 128 + wrow + i * 16 + rr;      // t (4 consecutive)
        f16x4 pk = {(f16)acc[i][j][0], (f16)acc[i][j][1],
                    (f16)acc[i][j][2], (f16)acc[i][j][3]};
        *(f16x4*)&vWoT[(long)bz * DIM * SEQ + (long)col * SEQ + row0] = pk;
      }
  }
}

// ---------------------------------------------------------------------------
// Final split-K=2 partials (grid (16,8,4) = 1024 blocks, 4/CU, plain stores)
// + atomic-free row sums (R10-proven). psum FP16 (R13-proven: |psum| O(1-10)).
// ---------------------------------------------------------------------------
__global__ __launch_bounds__(256, 4)
void gemm_final(const f16* __restrict__ Pb, const f16* __restrict__ Vw,
                f16* __restrict__ psum, float* __restrict__ rowsum)
{
  __shared__ __align__(16) f16 As[8192];
  __shared__ __align__(16) f16 Bs[8192];
  const int tid  = threadIdx.x;
  const int lane = tid & 63;
  const int wid  = tid >> 6;
  const int bm = blockIdx.x, bn = blockIdx.y;
  const int bz = blockIdx.z >> 1, kh = blockIdx.z & 1;

  const f16* Ag = Pb + (long)bz * SEQ * SEQ + (long)kh * 1024;
  const f16* Bg = Vw + (long)bz * DIM * SEQ + (long)kh * 1024;

  const int s_r  = tid >> 3;
  const int s_cb = (tid & 7) ^ (s_r & 7);
  const f16* Ab = Ag + (long)(bm * 128 + s_r) * 2048 + s_cb * 8;
  const f16* Bb = Bg + (long)(bn * 128 + s_r) * 2048 + s_cb * 8;

  const int l15 = lane & 15, l7 = lane & 7, lhi = lane >> 4;
  const int wrow = (wid >> 1) * 64;
  const int wcol = (wid & 1) * 64;
  const int ar = (wrow + l15) * 64;
  const int br = (wcol + l15) * 64;
  const int cb0 = ((0 + lhi) ^ l7) * 8;
  const int cb1 = ((4 + lhi) ^ l7) * 8;
  const bool do_rs = ((wid & 1) == 0);

  f32x4 acc[4][4] = {};
  float rsum[4] = {0.f, 0.f, 0.f, 0.f};

#pragma unroll
  for (int t = 0; t < 16; ++t){
    __syncthreads();
    GLOAD16(Ab + (long)t*64,                   &As[       tid*8]);
    GLOAD16(Ab + (long)t*64 + (long)32 * 2048, &As[2048 + tid*8]);
    GLOAD16(Ab + (long)t*64 + (long)64 * 2048, &As[4096 + tid*8]);
    GLOAD16(Ab + (long)t*64 + (long)96 * 2048, &As[6144 + tid*8]);
    GLOAD16(Bb + (long)t*64,                   &Bs[       tid*8]);
    GLOAD16(Bb + (long)t*64 + (long)32 * 2048, &Bs[2048 + tid*8]);
    GLOAD16(Bb + (long)t*64 + (long)64 * 2048, &Bs[4096 + tid*8]);
    GLOAD16(Bb + (long)t*64 + (long)96 * 2048, &Bs[6144 + tid*8]);
    __syncthreads();
    f16x8 af[4], bf[4];
#pragma unroll
    for (int i = 0; i < 4; i++) af[i] = *(const f16x8*)&As[ar + i * 1024 + cb0];
#pragma unroll
    for (int j = 0; j < 4; j++) bf[j] = *(const f16x8*)&Bs[br + j * 1024 + cb0];
#pragma unroll
    for (int i = 0; i < 4; i++)
#pragma unroll
      for (int j = 0; j < 4; j++)
        acc[i][j] = __builtin_amdgcn_mfma_f32_16x16x32_f16(af[i], bf[j], acc[i][j], 0, 0, 0);
    if (do_rs){
#pragma unroll
      for (int i = 0; i < 4; i++)
#pragma unroll
        for (int e = 0; e < 8; e++) rsum[i] += (float)af[i][e];
    }
#pragma unroll
    for (int i = 0; i < 4; i++) af[i] = *(const f16x8*)&As[ar + i * 1024 + cb1];
#pragma unroll
    for (int j = 0; j < 4; j++) bf[j] = *(const f16x8*)&Bs[br + j * 1024 + cb1];
#pragma unroll
    for (int i = 0; i < 4; i++)
#pragma unroll
      for (int j = 0; j < 4; j++)
        acc[i][j] = __builtin_amdgcn_mfma_f32_16x16x32_f16(af[i], bf[j], acc[i][j], 0, 0, 0);
    if (do_rs){
#pragma unroll
      for (int i = 0; i < 4; i++)
#pragma unroll
        for (int e = 0; e < 8; e++) rsum[i] += (float)af[i][e];
    }
  }

  if (do_rs){
#pragma unroll
    for (int i = 0; i < 4; i++){
      rsum[i] += __shfl_xor(rsum[i], 16, 64);
      rsum[i] += __shfl_xor(rsum[i], 32, 64);
    }
    if (bn == 0 && lane < 16){
#pragma unroll
      for (int i = 0; i < 4; i++)
        rowsum[(long)kh * MTOT + bz * SEQ + bm * 128 + wrow + i * 16 + lane] = rsum[i];
    }
  }

  const int cc = l15;
  const int rr = lhi * 4;
  f16* Po = psum + (long)kh * MTOT * DIM + (long)bz * SEQ * DIM;
#pragma unroll
  for (int i = 0; i < 4; i++)
#pragma unroll
    for (int j = 0; j < 4; j++){
      const int col = bn * 128 + wcol + j * 16 + cc;
#pragma unroll
      for (int r = 0; r < 4; r++){
        const int row = bm * 128 + wrow + i * 16 + rr + r;
        Po[(long)row * DIM + col] = (f16)acc[i][j][r];
      }
    }
}

// out = (psum0 + psum1) / (rs0 + rs1) + bo[col], psum f16, out fp32.
__global__ __launch_bounds__(256)
void combine_kernel(const f16* __restrict__ psum, const float* __restrict__ rowsum,
                    const float* __restrict__ bo, float* __restrict__ out)
{
  const long i = (long)blockIdx.x * 256 + threadIdx.x;   // 4-elem group index
  const int row = (int)(i >> 8);                         // global row 0..4095
  const int c4  = (int)(i & 255);
  f16x4 a = ((const f16x4*)psum)[i];
  f16x4 b = ((const f16x4*)(psum + (long)MTOT * DIM))[i];
  float4 bb = ((const float4*)bo)[c4];
  const float inv = 1.f / (rowsum[row] + rowsum[MTOT + row]);
  float4 o;
  o.x = ((float)a[0] + (float)b[0]) * inv + bb.x;
  o.y = ((float)a[1] + (float)b[1]) * inv + bb.y;
  o.z = ((float)a[2] + (float)b[2]) * inv + bb.z;
  o.w = ((float)a[3] + (float)b[3]) * inv + bb.w;
  ((float4*)out)[i] = o;
}

extern "C" void kernel_launch(void* const* d_in, const int* in_sizes, int n_in,
                              void* d_out, int out_size, void* d_ws, size_t ws_size,
                              hipStream_t stream){
  const float* x  = (const float*)d_in[0];
  const float* Wq = (const float*)d_in[1];
  const float* bq = (const float*)d_in[2];
  const float* Wk = (const float*)d_in[3];
  const float* bk = (const float*)d_in[4];
  const float* Wv = (const float*)d_in[5];
  const float* bv = (const float*)d_in[6];
  const float* Wo = (const float*)d_in[7];
  const float* bo = (const float*)d_in[8];
  float* out = (float*)d_out;

  char* ws = (char*)d_ws;
  size_t off = 0;
  auto alloc = [&](size_t bytes) -> char* {
    char* p = ws + off; off += (bytes + 255) & ~(size_t)255; return p;
  };

  f16* x16     = (f16*)alloc(2ull * MTOT * DIM);          // 8 MB
  f16* Wcat    = (f16*)alloc(2ull * 3 * DIM * DIM);       // 6 MB  [Wq;Wk;Wv]
  f16* Wo16    = (f16*)alloc(2ull * DIM * DIM);           // 2 MB
  f16* qbuf    = (f16*)alloc(2ull * MTOT * DIM);          // 8 MB  q dense
  f16* kbuf    = (f16*)alloc(2ull * MTOT * DIM);          // 8 MB  k dense
  f16* vbuf    = (f16*)alloc(2ull * MTOT * DIM);          // 8 MB  v row-major
  f16* Pbuf    = (f16*)alloc(2ull * NBATCH * SEQ * SEQ);  // 16 MB unnormalized exp
  f16* vWoT    = (f16*)alloc(2ull * NBATCH * DIM * SEQ);  // 8 MB  (v@Wo^T)^T [b][e][t]
  f16* psum    = (f16*)alloc(2ull * 2 * MTOT * DIM);      // 16.8 MB split-K partials (f16)
  float* rowsm = (float*)alloc(4ull * 2 * MTOT);          // 32 KB partial row sums

  if (off > ws_size){
    fill_kernel<<<(out_size + 255) / 256, 256, 0, stream>>>(out, 12345.0f, out_size);
    return;
  }

  cvt_all<<<8192, 256, 0, stream>>>(x, Wq, Wk, Wv, Wo, x16, Wcat, Wo16);

  // fused [q|k|v] = x @ [Wq;Wk;Wv]^T + bias  (768 blocks, XCD 2D-chunk remap)
  gemm_qkv<<<768, 256, 0, stream>>>(x16, Wcat, qbuf, kbuf, vbuf, bq, bk, bv);

  // merged: qk->P [0..511] and vWo^T [512..767], XCD-remapped, 3/CU
  gemm_merged<<<768, 256, 0, stream>>>(qbuf, kbuf, vbuf, Wo16, Pbuf, vWoT);

  // split-K=2 f16 partials + atomic-free row sums (grid 16x8x4 = 1024, 4/CU)
  gemm_final<<<dim3(SEQ / 128, DIM / 128, 2 * NBATCH), 256, 0, stream>>>(
      Pbuf, vWoT, psum, rowsm);

  // out = (p0+p1)/(rs0+rs1) + bo  (4096 blocks, f16 reads, float4 writes)
  combine_kernel<<<MTOT * DIM / 4 / 256, 256, 0, stream>>>(psum, rowsm, bo, out);
}

// Round 15
// 115.691 us; speedup vs baseline: 1.5429x; 1.0061x over previous
//
#include <hip/hip_runtime.h>
#include <hip/hip_fp16.h>
#include <stdint.h>

typedef _Float16 f16;
typedef __attribute__((ext_vector_type(8))) _Float16 f16x8;
typedef __attribute__((ext_vector_type(4))) _Float16 f16x4;
typedef __attribute__((ext_vector_type(4))) float f32x4;

#define SEQ 2048
#define DIM 1024
#define NBATCH 2
#define MTOT 4096  // NBATCH*SEQ

__global__ void fill_kernel(float* p, float v, int n){
  int i = blockIdx.x * 256 + threadIdx.x;
  if (i < n) p[i] = v;
}

// fp32->fp16 converts: blocks 0..4095 -> x, 4096..8191 -> weights.
__global__ void cvt_all(const float* __restrict__ x, const float* __restrict__ Wq,
                        const float* __restrict__ Wk, const float* __restrict__ Wv,
                        const float* __restrict__ Wo,
                        f16* __restrict__ x16, f16* __restrict__ Wcat, f16* __restrict__ Wo16){
  int b = blockIdx.x;
  const float* src; f16* dst; int i;
  if (b < 4096){
    src = x; dst = x16; i = b * 256 + threadIdx.x;
  } else {
    int t = (b - 4096) >> 10;
    i = ((b - 4096) & 1023) * 256 + threadIdx.x;
    src = t == 0 ? Wq : t == 1 ? Wk : t == 2 ? Wv : Wo;
    dst = (t == 3) ? Wo16 : Wcat + (size_t)t * DIM * DIM;
  }
  float4 v = ((const float4*)src)[i];
  ((f16x4*)dst)[i] = (f16x4){(f16)v.x, (f16)v.y, (f16)v.z, (f16)v.w};
}

#define GLOAD16(SRC, DST) __builtin_amdgcn_global_load_lds( \
    (__attribute__((address_space(1))) void*)(SRC), \
    (__attribute__((address_space(3))) void*)(DST), 16, 0, 0)

// theta -> unnormalized exp (shift 10, clamp 11). x->-inf: e1=inf -> sg=0, th=-1.
// P in [e^-9.65, e^11]; e^-9.65 = 6.4e-5 >= f16 min normal (by design of shift 10).
__device__ __forceinline__ float theta_exp(float v){
  const float e1 = __expf(-v);
  const float sg = 1.f / (1.f + e1);
  const float e2 = e1 * e1;             // e^{-2x}
  const float th = 2.f / (1.f + e2) - 1.f;
  const float theta = 0.5f + 0.2f * sg + 0.15f * th + 0.1f * fmaxf(v, 0.f);
  return __expf(fminf(theta - 10.f, 11.f));
}

// ---------------------------------------------------------------------------
// qkv: 256-thr 128x128 tile, BK=64, single-buffer, 2 barriers/tile. XOR
// swizzle (0 conflicts measured R3-R14). Grid 768 LINEAR with XCD 2D-chunk
// remap: XCD x gets bm in [(x&3)*8,+8), bn in [(x>>2)*12,+12).
// Epilogue: col<1024 -> qbuf(+bq), col<2048 -> kbuf(+bk), else vbuf(+bv).
// ---------------------------------------------------------------------------
__global__ __launch_bounds__(256, 3)
void gemm_qkv(const f16* __restrict__ A0, const f16* __restrict__ B0,
              f16* __restrict__ Oq, f16* __restrict__ Ok, f16* __restrict__ Ov,
              const float* __restrict__ c0, const float* __restrict__ c1,
              const float* __restrict__ c2)
{
  __shared__ __align__(16) f16 As[8192];   // 128 x 64 f16
  __shared__ __align__(16) f16 Bs[8192];
  const int tid  = threadIdx.x;
  const int lane = tid & 63;
  const int wid  = tid >> 6;
  const int r = blockIdx.x;
  const int x = r & 7, i5 = r >> 3;        // i5 0..95
  const int bm = (x & 3) * 8 + (i5 & 7);   // 0..31
  const int bn = (x >> 2) * 12 + (i5 >> 3);// 0..23

  const int s_r  = tid >> 3;            // 0..31
  const int s_cb = (tid & 7) ^ (s_r & 7);
  const f16* Ab = A0 + (long)(bm * 128 + s_r) * DIM + s_cb * 8;
  const f16* Bb = B0 + (long)(bn * 128 + s_r) * DIM + s_cb * 8;

  const int l15 = lane & 15, l7 = lane & 7, lhi = lane >> 4;
  const int wrow = (wid >> 1) * 64;
  const int wcol = (wid & 1) * 64;
  const int ar = (wrow + l15) * 64;
  const int br = (wcol + l15) * 64;
  const int cb0 = ((0 + lhi) ^ l7) * 8;
  const int cb1 = ((4 + lhi) ^ l7) * 8;

  f32x4 acc[4][4] = {};

#pragma unroll
  for (int t = 0; t < 16; ++t){
    __syncthreads();
    GLOAD16(Ab + (long)t*64,                  &As[       tid*8]);
    GLOAD16(Ab + (long)t*64 + (long)32 * DIM, &As[2048 + tid*8]);
    GLOAD16(Ab + (long)t*64 + (long)64 * DIM, &As[4096 + tid*8]);
    GLOAD16(Ab + (long)t*64 + (long)96 * DIM, &As[6144 + tid*8]);
    GLOAD16(Bb + (long)t*64,                  &Bs[       tid*8]);
    GLOAD16(Bb + (long)t*64 + (long)32 * DIM, &Bs[2048 + tid*8]);
    GLOAD16(Bb + (long)t*64 + (long)64 * DIM, &Bs[4096 + tid*8]);
    GLOAD16(Bb + (long)t*64 + (long)96 * DIM, &Bs[6144 + tid*8]);
    __syncthreads();
    f16x8 af[4], bf[4];
#pragma unroll
    for (int i = 0; i < 4; i++) af[i] = *(const f16x8*)&As[ar + i * 1024 + cb0];
#pragma unroll
    for (int j = 0; j < 4; j++) bf[j] = *(const f16x8*)&Bs[br + j * 1024 + cb0];
#pragma unroll
    for (int i = 0; i < 4; i++)
#pragma unroll
      for (int j = 0; j < 4; j++)
        acc[i][j] = __builtin_amdgcn_mfma_f32_16x16x32_f16(af[i], bf[j], acc[i][j], 0, 0, 0);
#pragma unroll
    for (int i = 0; i < 4; i++) af[i] = *(const f16x8*)&As[ar + i * 1024 + cb1];
#pragma unroll
    for (int j = 0; j < 4; j++) bf[j] = *(const f16x8*)&Bs[br + j * 1024 + cb1];
#pragma unroll
    for (int i = 0; i < 4; i++)
#pragma unroll
      for (int j = 0; j < 4; j++)
        acc[i][j] = __builtin_amdgcn_mfma_f32_16x16x32_f16(af[i], bf[j], acc[i][j], 0, 0, 0);
  }

  const int cc = l15;
  const int rr = lhi * 4;
#pragma unroll
  for (int i = 0; i < 4; i++)
#pragma unroll
    for (int j = 0; j < 4; j++){
      const int col = bn * 128 + wcol + j * 16 + cc;
      f16* dst; int dcol; float badd;
      if (col < 1024){       dst = Oq; dcol = col;        badd = c0[dcol]; }
      else if (col < 2048){  dst = Ok; dcol = col - 1024; badd = c1[dcol]; }
      else {                 dst = Ov; dcol = col - 2048; badd = c2[dcol]; }
#pragma unroll
      for (int rq = 0; rq < 4; rq++){
        const int row = bm * 128 + wrow + i * 16 + rr + rq;
        dst[(long)row * DIM + dcol] = (f16)(acc[i][j][rq] + badd);
      }
    }
}

// ---------------------------------------------------------------------------
// Merged qk + vWo (128x128 tiles, 512 + 256 = 768 blocks, 3/CU), XCD remap.
// Outputs now SPLIT per kh-half into dense ld=1024 buffers (R15) so the
// final GEMM's staged panels are dense:
//   qk (r<512):   P = theta_exp(q@k^T) -> P0 (col<1024) / P1 (col>=1024).
//   vWo (r>=512): (v@Wo^T)^T -> V0 (t<1024) / V1 (t>=1024), [b][e][t'&1023].
// Half-selector is uniform per block (col-half = bn>>3, t-half = bm>>3).
// ---------------------------------------------------------------------------
__global__ __launch_bounds__(256, 3)
void gemm_merged(const f16* __restrict__ qbuf, const f16* __restrict__ kbuf,
                 const f16* __restrict__ vbuf, const f16* __restrict__ Wo16,
                 f16* __restrict__ P0, f16* __restrict__ P1,
                 f16* __restrict__ V0, f16* __restrict__ V1)
{
  __shared__ __align__(16) f16 As[8192];
  __shared__ __align__(16) f16 Bs[8192];
  const int tid  = threadIdx.x;
  const int lane = tid & 63;
  const int wid  = tid >> 6;
  const int l15 = lane & 15, l7 = lane & 7, lhi = lane >> 4;
  const int s_r  = tid >> 3;
  const int s_cb = (tid & 7) ^ (s_r & 7);
  const int cb0 = ((0 + lhi) ^ l7) * 8;
  const int cb1 = ((4 + lhi) ^ l7) * 8;
  const int cc = l15, rr = lhi * 4;
  const int wrow = (wid >> 1) * 64;
  const int wcol = (wid & 1) * 64;
  const int ar = (wrow + l15) * 64;
  const int br = (wcol + l15) * 64;
  const int r = blockIdx.x;

  const f16 *Ab, *Bb;
  int bm, bn, bz;
  bool isQK;
  if (r < 512){
    isQK = true;
    const int x = r & 7, i5 = r >> 3;
    bz = x >> 2;
    bn = (x & 3) * 4 + (i5 & 3);
    bm = i5 >> 2;
    Ab = qbuf + (long)bz * SEQ * DIM + (long)(bm * 128 + s_r) * DIM + s_cb * 8;
    Bb = kbuf + (long)bz * SEQ * DIM + (long)(bn * 128 + s_r) * DIM + s_cb * 8;
  } else {
    isQK = false;
    const int rr2 = r - 512;
    const int x = rr2 & 7, i5 = rr2 >> 3;
    bz = x >> 2;
    bn = (x & 3) * 2 + (i5 & 1);
    bm = i5 >> 1;
    Ab = vbuf + (long)bz * SEQ * DIM + (long)(bm * 128 + s_r) * DIM + s_cb * 8;
    Bb = Wo16 + (long)(bn * 128 + s_r) * DIM + s_cb * 8;
  }

  f32x4 acc[4][4] = {};

#pragma unroll
  for (int t = 0; t < 16; ++t){
    __syncthreads();
    GLOAD16(Ab + (long)t*64,                  &As[       tid*8]);
    GLOAD16(Ab + (long)t*64 + (long)32 * DIM, &As[2048 + tid*8]);
    GLOAD16(Ab + (long)t*64 + (long)64 * DIM, &As[4096 + tid*8]);
    GLOAD16(Ab + (long)t*64 + (long)96 * DIM, &As[6144 + tid*8]);
    GLOAD16(Bb + (long)t*64,                  &Bs[       tid*8]);
    GLOAD16(Bb + (long)t*64 + (long)32 * DIM, &Bs[2048 + tid*8]);
    GLOAD16(Bb + (long)t*64 + (long)64 * DIM, &Bs[4096 + tid*8]);
    GLOAD16(Bb + (long)t*64 + (long)96 * DIM, &Bs[6144 + tid*8]);
    __syncthreads();
    f16x8 af[4], bf[4];
#pragma unroll
    for (int i = 0; i < 4; i++) af[i] = *(const f16x8*)&As[ar + i * 1024 + cb0];
#pragma unroll
    for (int j = 0; j < 4; j++) bf[j] = *(const f16x8*)&Bs[br + j * 1024 + cb0];
#pragma unroll
    for (int i = 0; i < 4; i++)
#pragma unroll
      for (int j = 0; j < 4; j++)
        acc[i][j] = __builtin_amdgcn_mfma_f32_16x16x32_f16(af[i], bf[j], acc[i][j], 0, 0, 0);
#pragma unroll
    for (int i = 0; i < 4; i++) af[i] = *(const f16x8*)&As[ar + i * 1024 + cb1];
#pragma unroll
    for (int j = 0; j < 4; j++) bf[j] = *(const f16x8*)&Bs[br + j * 1024 + cb1];
#pragma unroll
    for (int i = 0; i < 4; i++)
#pragma unroll
      for (int j = 0; j < 4; j++)
        acc[i][j] = __builtin_amdgcn_mfma_f32_16x16x32_f16(af[i], bf[j], acc[i][j], 0, 0, 0);
  }

  if (isQK){
    f16* Ph = (bn < 8) ? P0 : P1;          // col-half uniform per block
#pragma unroll
    for (int i = 0; i < 4; i++)
#pragma unroll
      for (int rq = 0; rq < 4; rq++){
        const int row = bm * 128 + wrow + i * 16 + rr + rq;
#pragma unroll
        for (int j = 0; j < 4; j++){
          const int col = bn * 128 + wcol + j * 16 + cc;
          Ph[(long)bz * SEQ * 1024 + (long)row * 1024 + (col & 1023)] =
              (f16)theta_exp(acc[i][j][rq]);
        }
      }
  } else {
    f16* Vh = (bm < 8) ? V0 : V1;          // t-half uniform per block
#pragma unroll
    for (int i = 0; i < 4; i++)
#pragma unroll
      for (int j = 0; j < 4; j++){
        const int col = bn * 128 + wcol + j * 16 + cc;       // e
        const int row0 = bm * 128 + wrow + i * 16 + rr;      // t (4 consecutive)
        f16x4 pk = {(f16)acc[i][j][0], (f16)acc[i][j][1],
                    (f16)acc[i][j][2], (f16)acc[i][j][3]};
        *(f16x4*)&Vh[(long)bz * DIM * 1024 + (long)col * 1024 + (row0 & 1023)] = pk;
      }
  }
}

// ---------------------------------------------------------------------------
// Final split-K=2 partials, grid 512 LINEAR (2 blocks/CU), dense ld=1024
// operands (R15) + XCD chunk map: XCD pair x>>1 handles one z4=(bz,kh);
// per XCD: 16 A-panels (4 MB, read 4x) + 4 B-panels (1 MB), co-resident.
// + atomic-free row sums (R10) and f16 psum (R13).
// ---------------------------------------------------------------------------
__global__ __launch_bounds__(256, 4)
void gemm_final(const f16* __restrict__ P0, const f16* __restrict__ P1,
                const f16* __restrict__ V0, const f16* __restrict__ V1,
                f16* __restrict__ psum, float* __restrict__ rowsum)
{
  __shared__ __align__(16) f16 As[8192];
  __shared__ __align__(16) f16 Bs[8192];
  const int tid  = threadIdx.x;
  const int lane = tid & 63;
  const int wid  = tid >> 6;
  const int r = blockIdx.x;                // 0..511
  const int x = r & 7, i5 = r >> 3;        // i5 0..63
  const int z4 = x >> 1;                   // 0..3
  const int bz = z4 >> 1, kh = z4 & 1;
  const int bn = (x & 1) * 4 + (i5 & 3);   // 0..7
  const int bm = i5 >> 2;                  // 0..15

  const f16* Ag = (kh ? P1 : P0) + (long)bz * SEQ * 1024;
  const f16* Bg = (kh ? V1 : V0) + (long)bz * DIM * 1024;

  const int s_r  = tid >> 3;
  const int s_cb = (tid & 7) ^ (s_r & 7);
  const f16* Ab = Ag + (long)(bm * 128 + s_r) * 1024 + s_cb * 8;
  const f16* Bb = Bg + (long)(bn * 128 + s_r) * 1024 + s_cb * 8;

  const int l15 = lane & 15, l7 = lane & 7, lhi = lane >> 4;
  const int wrow = (wid >> 1) * 64;
  const int wcol = (wid & 1) * 64;
  const int ar = (wrow + l15) * 64;
  const int br = (wcol + l15) * 64;
  const int cb0 = ((0 + lhi) ^ l7) * 8;
  const int cb1 = ((4 + lhi) ^ l7) * 8;
  const bool do_rs = ((wid & 1) == 0);

  f32x4 acc[4][4] = {};
  float rsum[4] = {0.f, 0.f, 0.f, 0.f};

#pragma unroll
  for (int t = 0; t < 16; ++t){
    __syncthreads();
    GLOAD16(Ab + (long)t*64,                   &As[       tid*8]);
    GLOAD16(Ab + (long)t*64 + (long)32 * 1024, &As[2048 + tid*8]);
    GLOAD16(Ab + (long)t*64 + (long)64 * 1024, &As[4096 + tid*8]);
    GLOAD16(Ab + (long)t*64 + (long)96 * 1024, &As[6144 + tid*8]);
    GLOAD16(Bb + (long)t*64,                   &Bs[       tid*8]);
    GLOAD16(Bb + (long)t*64 + (long)32 * 1024, &Bs[2048 + tid*8]);
    GLOAD16(Bb + (long)t*64 + (long)64 * 1024, &Bs[4096 + tid*8]);
    GLOAD16(Bb + (long)t*64 + (long)96 * 1024, &Bs[6144 + tid*8]);
    __syncthreads();
    f16x8 af[4], bf[4];
#pragma unroll
    for (int i = 0; i < 4; i++) af[i] = *(const f16x8*)&As[ar + i * 1024 + cb0];
#pragma unroll
    for (int j = 0; j < 4; j++) bf[j] = *(const f16x8*)&Bs[br + j * 1024 + cb0];
#pragma unroll
    for (int i = 0; i < 4; i++)
#pragma unroll
      for (int j = 0; j < 4; j++)
        acc[i][j] = __builtin_amdgcn_mfma_f32_16x16x32_f16(af[i], bf[j], acc[i][j], 0, 0, 0);
    if (do_rs){
#pragma unroll
      for (int i = 0; i < 4; i++)
#pragma unroll
        for (int e = 0; e < 8; e++) rsum[i] += (float)af[i][e];
    }
#pragma unroll
    for (int i = 0; i < 4; i++) af[i] = *(const f16x8*)&As[ar + i * 1024 + cb1];
#pragma unroll
    for (int j = 0; j < 4; j++) bf[j] = *(const f16x8*)&Bs[br + j * 1024 + cb1];
#pragma unroll
    for (int i = 0; i < 4; i++)
#pragma unroll
      for (int j = 0; j < 4; j++)
        acc[i][j] = __builtin_amdgcn_mfma_f32_16x16x32_f16(af[i], bf[j], acc[i][j], 0, 0, 0);
    if (do_rs){
#pragma unroll
      for (int i = 0; i < 4; i++)
#pragma unroll
        for (int e = 0; e < 8; e++) rsum[i] += (float)af[i][e];
    }
  }

  if (do_rs){
#pragma unroll
    for (int i = 0; i < 4; i++){
      rsum[i] += __shfl_xor(rsum[i], 16, 64);
      rsum[i] += __shfl_xor(rsum[i], 32, 64);
    }
    if (bn == 0 && lane < 16){
#pragma unroll
      for (int i = 0; i < 4; i++)
        rowsum[(long)kh * MTOT + bz * SEQ + bm * 128 + wrow + i * 16 + lane] = rsum[i];
    }
  }

  const int cc = l15;
  const int rr = lhi * 4;
  f16* Po = psum + (long)kh * MTOT * DIM + (long)bz * SEQ * DIM;
#pragma unroll
  for (int i = 0; i < 4; i++)
#pragma unroll
    for (int j = 0; j < 4; j++){
      const int col = bn * 128 + wcol + j * 16 + cc;
#pragma unroll
      for (int rq = 0; rq < 4; rq++){
        const int row = bm * 128 + wrow + i * 16 + rr + rq;
        Po[(long)row * DIM + col] = (f16)acc[i][j][rq];
      }
    }
}

// out = (psum0 + psum1) / (rs0 + rs1) + bo[col], psum f16, out fp32.
__global__ __launch_bounds__(256)
void combine_kernel(const f16* __restrict__ psum, const float* __restrict__ rowsum,
                    const float* __restrict__ bo, float* __restrict__ out)
{
  const long i = (long)blockIdx.x * 256 + threadIdx.x;   // 4-elem group index
  const int row = (int)(i >> 8);                         // global row 0..4095
  const int c4  = (int)(i & 255);
  f16x4 a = ((const f16x4*)psum)[i];
  f16x4 b = ((const f16x4*)(psum + (long)MTOT * DIM))[i];
  float4 bb = ((const float4*)bo)[c4];
  const float inv = 1.f / (rowsum[row] + rowsum[MTOT + row]);
  float4 o;
  o.x = ((float)a[0] + (float)b[0]) * inv + bb.x;
  o.y = ((float)a[1] + (float)b[1]) * inv + bb.y;
  o.z = ((float)a[2] + (float)b[2]) * inv + bb.z;
  o.w = ((float)a[3] + (float)b[3]) * inv + bb.w;
  ((float4*)out)[i] = o;
}

extern "C" void kernel_launch(void* const* d_in, const int* in_sizes, int n_in,
                              void* d_out, int out_size, void* d_ws, size_t ws_size,
                              hipStream_t stream){
  const float* x  = (const float*)d_in[0];
  const float* Wq = (const float*)d_in[1];
  const float* bq = (const float*)d_in[2];
  const float* Wk = (const float*)d_in[3];
  const float* bk = (const float*)d_in[4];
  const float* Wv = (const float*)d_in[5];
  const float* bv = (const float*)d_in[6];
  const float* Wo = (const float*)d_in[7];
  const float* bo = (const float*)d_in[8];
  float* out = (float*)d_out;

  char* ws = (char*)d_ws;
  size_t off = 0;
  auto alloc = [&](size_t bytes) -> char* {
    char* p = ws + off; off += (bytes + 255) & ~(size_t)255; return p;
  };

  f16* x16     = (f16*)alloc(2ull * MTOT * DIM);          // 8 MB
  f16* Wcat    = (f16*)alloc(2ull * 3 * DIM * DIM);       // 6 MB  [Wq;Wk;Wv]
  f16* Wo16    = (f16*)alloc(2ull * DIM * DIM);           // 2 MB
  f16* qbuf    = (f16*)alloc(2ull * MTOT * DIM);          // 8 MB  q dense
  f16* kbuf    = (f16*)alloc(2ull * MTOT * DIM);          // 8 MB  k dense
  f16* vbuf    = (f16*)alloc(2ull * MTOT * DIM);          // 8 MB  v row-major
  f16* P0      = (f16*)alloc(2ull * NBATCH * SEQ * 1024); // 8 MB  P cols 0..1023
  f16* P1      = (f16*)alloc(2ull * NBATCH * SEQ * 1024); // 8 MB  P cols 1024..2047
  f16* V0      = (f16*)alloc(2ull * NBATCH * DIM * 1024); // 4 MB  vWo^T t 0..1023
  f16* V1      = (f16*)alloc(2ull * NBATCH * DIM * 1024); // 4 MB  vWo^T t 1024..2047
  f16* psum    = (f16*)alloc(2ull * 2 * MTOT * DIM);      // 16.8 MB split-K partials
  float* rowsm = (float*)alloc(4ull * 2 * MTOT);          // 32 KB partial row sums

  if (off > ws_size){
    fill_kernel<<<(out_size + 255) / 256, 256, 0, stream>>>(out, 12345.0f, out_size);
    return;
  }

  cvt_all<<<8192, 256, 0, stream>>>(x, Wq, Wk, Wv, Wo, x16, Wcat, Wo16);

  // fused [q|k|v] = x @ [Wq;Wk;Wv]^T + bias  (768 blocks, XCD 2D-chunk remap)
  gemm_qkv<<<768, 256, 0, stream>>>(x16, Wcat, qbuf, kbuf, vbuf, bq, bk, bv);

  // merged: qk->P0/P1 [0..511] and vWo^T->V0/V1 [512..767], XCD-remapped
  gemm_merged<<<768, 256, 0, stream>>>(qbuf, kbuf, vbuf, Wo16, P0, P1, V0, V1);

  // split-K=2 f16 partials + row sums (512 blocks, dense panels, XCD chunks)
  gemm_final<<<512, 256, 0, stream>>>(P0, P1, V0, V1, psum, rowsm);

  // out = (p0+p1)/(rs0+rs1) + bo  (4096 blocks, f16 reads, float4 writes)
  combine_kernel<<<MTOT * DIM / 4 / 256, 256, 0, stream>>>(psum, rowsm, bo, out);
}